// Round 1
// 1212.612 us; speedup vs baseline: 1.1080x; 1.1080x over previous
//
#include <hip/hip_runtime.h>
#include <hip/hip_bf16.h>
#include <hip/hip_fp16.h>

// CellTrack GNN, MI355X — R14: fully-vectorized f16x8 gather + sMsg removed.
// R13: 1.343ms; k_edge_mlp 755us latency-bound (HBM 12%, Mfma 11.6%, occ 35%).
// R14: (a) gather phase all f16x8 (X1 mirror padded to 16; feature columns
// permuted in k_prep so every LDS store is an aligned ds_write_b128);
// (b) xs kept in regs across GEMM1/2, parked into the dead hid overlay for
// the msg GEMM (Wmsg halves swapped in k_prep) -> sMsg LDS buffer deleted,
// 52.7KB -> 35.5KB -> 4 blocks/CU.
// ws: AGG fp32 | EB fp16 | WT fp16 | XH | XNH | X1P | X2H  = ~194MB.

using fp16 = __half;
typedef _Float16 h16;
typedef _Float16 f16x8 __attribute__((ext_vector_type(8)));
typedef float f32x4 __attribute__((ext_vector_type(4)));

#define NN 50000
#define EE 500000
#define EPSC 1e-8f

__device__ __forceinline__ float reluf(float v){ return v > 0.f ? v : 0.f; }

// WT sub-buffer offsets (halves)
#define OFF_E1   0         // [256][544]  (527 real, permuted col order)
#define OFF_E2   139264    // [128][256]
#define OFF_MSG  172032    // [128][256]  ([e|xs] order)
#define OFF_NODE 204800    // [128][256]
#define OFF_MP1  237568    // [256][384]
#define OFF_MP2  335872    // [128][256]
#define OFF_C1   368640    // [64][128]
#define WT_TOTAL 376832

// ---------------------------------------------------------------------------
// k_prep: fp32 weights -> fp16 transposed [n][kP] (zero-pad k >= kreal).
// E1 feature column order (k -> orig We1 row):
//   [0,128)   xs        -> 142+k
//   [128,256) xt        -> 270+(k-128)
//   [256,384) |xs-xt|   -> 398+(k-256)
//   [384,512) |x2s-x2t| -> 13+(k-384)
//   [512,525) |x1s-x1t| -> k-512        ([525,528) zero pad inside block)
//   528       sim1      -> 141
//   529       sim2      -> 526          ([530,544) zero pad)
// MSG order [e|xs]: k<128 -> Wmsg row 128+k ; k>=128 -> Wmsg row k-128.
// ---------------------------------------------------------------------------
__global__ __launch_bounds__(256) void k_prep(
    const float* __restrict__ We1, const float* __restrict__ We2,
    const float* __restrict__ Wmsg, const float* __restrict__ Wnode,
    const float* __restrict__ Wmp1, const float* __restrict__ Wmp2,
    const float* __restrict__ Wc1, h16* __restrict__ WT)
{
  int idx = blockIdx.x * 256 + threadIdx.x;
  if (idx >= WT_TOTAL) return;
  h16 v;
  if (idx < OFF_E2) {
    const int L = idx, n = L / 544, k = L % 544;
    int r;
    if      (k < 128) r = 142 + k;
    else if (k < 256) r = 270 + (k - 128);
    else if (k < 384) r = 398 + (k - 256);
    else if (k < 512) r = 13 + (k - 384);
    else if (k < 525) r = k - 512;
    else if (k == 528) r = 141;
    else if (k == 529) r = 526;
    else r = -1;
    v = (h16)((r >= 0) ? We1[r * 256 + n] : 0.f);
  } else if (idx < OFF_MSG) {
    const int L = idx - OFF_E2, n = L >> 8, k = L & 255;
    v = (h16)We2[k * 128 + n];
  } else if (idx < OFF_NODE) {
    const int L = idx - OFF_MSG, n = L >> 8, k = L & 255;
    const int ko = (k < 128) ? (128 + k) : (k - 128);   // [e|xs] order
    v = (h16)Wmsg[ko * 128 + n];
  } else if (idx < OFF_MP1) {
    const int L = idx - OFF_NODE, n = L >> 8, k = L & 255;
    v = (h16)Wnode[k * 128 + n];
  } else if (idx < OFF_MP2) {
    const int L = idx - OFF_MP1, n = L / 384, k = L % 384;
    v = (h16)Wmp1[k * 256 + n];
  } else if (idx < OFF_C1) {
    const int L = idx - OFF_MP2, n = L >> 8, k = L & 255;
    v = (h16)Wmp2[k * 128 + n];
  } else {
    const int L = idx - OFF_C1, n = L >> 7, k = L & 127;
    v = (h16)Wc1[k * 64 + n];
  }
  WT[idx] = v;
}

// k_cvt: x1 -> fp16 mirror padded to 16/row (vector-gatherable), x2 -> fp16.
__global__ __launch_bounds__(256) void k_cvt(
    const float* __restrict__ x1, const float* __restrict__ x2,
    h16* __restrict__ X1P, h16* __restrict__ X2H)
{
  const int idx = blockIdx.x * 256 + threadIdx.x;
  if (idx < NN * 16) {
    const int nn = idx >> 4, j = idx & 15;
    X1P[idx] = (h16)((j < 13) ? x1[nn * 13 + j] : 0.f);
  }
  const int i2 = idx - NN * 16;
  if (i2 >= 0 && i2 < NN * 128) X2H[i2] = (h16)x2[i2];
}

// ---------------------------------------------------------------------------
// MFMA GEMM: C[ROWS][UDIM] = act(A[ROWS][kP] @ WT^T + b). 256 thr = 4 waves.
// Wave w: all ROWS x cols [w*UDIM/4..). A fp16 LDS stride lda (≡8 mod 16).
// WT fp16 global [UDIM][kP] (L2-resident). Barrier before emits (A reads
// done -> overlays safe) and after (emits visible).
// ---------------------------------------------------------------------------
template<int ROWS, int UDIM, bool RELU, typename F>
__device__ __forceinline__ void mfma_gemm(const h16* sA, int lda, int kP,
    const h16* __restrict__ WT, const float* __restrict__ bias, F emit)
{
  constexpr int RT = ROWS / 16;
  constexpr int NPW = UDIM / 4;
  constexpr int NT = NPW / 16;
  const int tid = threadIdx.x;
  const int wave = tid >> 6;
  const int lane = tid & 63;
  const int m = lane & 15;
  const int quad = lane >> 4;
  const int n0 = wave * NPW;
  f32x4 acc[RT][NT];
#pragma unroll
  for (int r = 0; r < RT; ++r)
#pragma unroll
    for (int j = 0; j < NT; ++j) acc[r][j] = (f32x4){0.f, 0.f, 0.f, 0.f};

  for (int k0 = 0; k0 < kP; k0 += 32) {
    f16x8 bf[NT];
#pragma unroll
    for (int j = 0; j < NT; ++j)
      bf[j] = *reinterpret_cast<const f16x8*>(
          &WT[(size_t)(n0 + j * 16 + m) * kP + k0 + quad * 8]);
#pragma unroll
    for (int r = 0; r < RT; ++r) {
      const f16x8 af = *reinterpret_cast<const f16x8*>(
          &sA[(r * 16 + m) * lda + k0 + quad * 8]);
#pragma unroll
      for (int j = 0; j < NT; ++j)
        acc[r][j] = __builtin_amdgcn_mfma_f32_16x16x32_f16(af, bf[j], acc[r][j], 0, 0, 0);
    }
  }
  __syncthreads();
#pragma unroll
  for (int r = 0; r < RT; ++r)
#pragma unroll
    for (int j = 0; j < NT; ++j) {
      const int col = n0 + j * 16 + m;
      const float bb = bias[col];
#pragma unroll
      for (int g = 0; g < 4; ++g) {
        const int row = r * 16 + quad * 4 + g;
        float v = acc[r][j][g] + bb;
        if (RELU) v = reluf(v);
        emit(row, col, v);
      }
    }
  __syncthreads();
}

// ---------------------------------------------------------------------------
// K0: node encoder (fp32 VALU). 4 nodes/block. Output: XH fp16.
// ---------------------------------------------------------------------------
__global__ __launch_bounds__(256) void k_node_enc(
    const float* __restrict__ x1, const float* __restrict__ x2,
    const float* __restrict__ Wh1, const float* __restrict__ bh1,
    const float* __restrict__ Wh2, const float* __restrict__ bh2,
    const float* __restrict__ Wl1, const float* __restrict__ bl1,
    const float* __restrict__ Wl2, const float* __restrict__ bl2,
    h16* __restrict__ XH)
{
  __shared__ float sx1[4][13];
  __shared__ float sx2[4][128];
  __shared__ float sh1[4][257];
  __shared__ float sh2[4][257];
  const int tid = threadIdx.x;
  const int node0 = blockIdx.x * 4;

  if (tid < 52) {
    const int n = tid / 13, k = tid % 13;
    sx1[n][k] = x1[(node0 + n) * 13 + k];
  }
  for (int L = tid; L < 512; L += 256) {
    const int n = L >> 7, k = L & 127;
    sx2[n][k] = x2[(size_t)(node0 + n) * 128 + k];
  }
  __syncthreads();

  {
    const int u = tid;
    float a0 = 0.f, a1 = 0.f, a2 = 0.f, a3 = 0.f;
    for (int k = 0; k < 13; ++k) {
      const float w = Wh1[k * 256 + u];
      a0 += sx1[0][k] * w; a1 += sx1[1][k] * w;
      a2 += sx1[2][k] * w; a3 += sx1[3][k] * w;
    }
    const float b = bh1[u];
    sh1[0][u] = reluf(a0 + b); sh1[1][u] = reluf(a1 + b);
    sh1[2][u] = reluf(a2 + b); sh1[3][u] = reluf(a3 + b);

    float c0 = 0.f, c1 = 0.f, c2 = 0.f, c3 = 0.f;
    for (int k = 0; k < 128; ++k) {
      const float w = Wl1[k * 256 + u];
      c0 += sx2[0][k] * w; c1 += sx2[1][k] * w;
      c2 += sx2[2][k] * w; c3 += sx2[3][k] * w;
    }
    const float b2 = bl1[u];
    sh2[0][u] = reluf(c0 + b2); sh2[1][u] = reluf(c1 + b2);
    sh2[2][u] = reluf(c2 + b2); sh2[3][u] = reluf(c3 + b2);
  }
  __syncthreads();

  {
    const int c = tid & 127;
    const int half = tid >> 7;
    float a0 = 0.f, a1 = 0.f;
    if (c < 32) {
      for (int k = 0; k < 256; ++k) {
        const float w = Wh2[k * 32 + c];
        a0 += sh1[half][k] * w; a1 += sh1[half + 2][k] * w;
      }
      const float b = bh2[c];
      XH[(size_t)(node0 + half) * 128 + c]     = (h16)(a0 + b);
      XH[(size_t)(node0 + half + 2) * 128 + c] = (h16)(a1 + b);
    } else {
      const int cc = c - 32;
      for (int k = 0; k < 256; ++k) {
        const float w = Wl2[k * 96 + cc];
        a0 += sh2[half][k] * w; a1 += sh2[half + 2][k] * w;
      }
      const float b = bl2[cc];
      XH[(size_t)(node0 + half) * 128 + c]     = (h16)(a0 + b);
      XH[(size_t)(node0 + half + 2) * 128 + c] = (h16)(a1 + b);
    }
  }
}

// ---------------------------------------------------------------------------
// K2: FUSED edge features + e-MLP (544p->256->128) + msg GEMM + atomic segsum.
// 32 edges/block (E = 32*15625), 8 thr/edge. All gathers f16x8 (16B).
// sFeat [32][552] 34.5KB; hid overlays stride 264 after GEMM1; e (cols 0-128)
// + reg-parked xs (cols 128-256) overlay for the msg GEMM. 4 blocks/CU.
// ---------------------------------------------------------------------------
__global__ __launch_bounds__(256, 4) void k_edge_mlp(
    const h16* __restrict__ X1P, const h16* __restrict__ X2H,
    const int* __restrict__ ei, const h16* __restrict__ XH,
    const h16* __restrict__ WT,
    const float* __restrict__ be1, const float* __restrict__ be2,
    const float* __restrict__ bmsg,
    h16* __restrict__ EB, float* __restrict__ AGG)
{
  __shared__ __align__(16) h16 sFeat[32 * 552];
  __shared__ int strg[32];
  const int tid = threadIdx.x;
  const long e0 = (long)blockIdx.x * 32;
  const int n = tid >> 3;
  const int q = tid & 7;
  h16* Arow = &sFeat[n * 552];
  f16x8 xsv0, xsv1;   // xs chunk lives in regs until the msg GEMM

  {
    const int s = ei[e0 + n];
    const int t = ei[(long)EE + e0 + n];
    if (q == 0) strg[n] = t;
    float ds = 0.f, ns = 0.f, nt = 0.f;
    if (q < 2) {                                   // handcrafted 13 (pad 16)
      const f16x8 a = *(const f16x8*)&X1P[s * 16 + q * 8];
      const f16x8 b = *(const f16x8*)&X1P[t * 16 + q * 8];
      f16x8 d;
#pragma unroll
      for (int i = 0; i < 8; ++i) {
        const float av = (float)a[i], bv = (float)b[i];
        ds += av * bv; ns += av * av; nt += bv * bv;
        d[i] = (h16)fabsf(av - bv);
      }
      *(f16x8*)&Arow[512 + q * 8] = d;
    }
#pragma unroll
    for (int c = 0; c < 2; ++c) {                  // learned 128
      const f16x8 a = *(const f16x8*)&X2H[(size_t)s * 128 + q * 16 + c * 8];
      const f16x8 b = *(const f16x8*)&X2H[(size_t)t * 128 + q * 16 + c * 8];
      f16x8 d;
#pragma unroll
      for (int i = 0; i < 8; ++i) {
        const float av = (float)a[i], bv = (float)b[i];
        ds += av * bv; ns += av * av; nt += bv * bv;
        d[i] = (h16)fabsf(av - bv);
      }
      *(f16x8*)&Arow[384 + q * 16 + c * 8] = d;
    }
    ds += __shfl_xor(ds, 1); ds += __shfl_xor(ds, 2); ds += __shfl_xor(ds, 4);
    ns += __shfl_xor(ns, 1); ns += __shfl_xor(ns, 2); ns += __shfl_xor(ns, 4);
    nt += __shfl_xor(nt, 1); nt += __shfl_xor(nt, 2); nt += __shfl_xor(nt, 4);
    if (q == 0)
      Arow[528] = (h16)(ds / (fmaxf(sqrtf(ns), EPSC) * fmaxf(sqrtf(nt), EPSC)));

    float ds2 = 0.f, ns2 = 0.f, nt2 = 0.f;
#pragma unroll
    for (int c = 0; c < 2; ++c) {                  // encoded nodes
      const f16x8 a = *(const f16x8*)&XH[(size_t)s * 128 + q * 16 + c * 8];
      const f16x8 b = *(const f16x8*)&XH[(size_t)t * 128 + q * 16 + c * 8];
      if (c == 0) xsv0 = a; else xsv1 = a;
      f16x8 d;
#pragma unroll
      for (int i = 0; i < 8; ++i) {
        const float av = (float)a[i], bv = (float)b[i];
        ds2 += av * bv; ns2 += av * av; nt2 += bv * bv;
        d[i] = (h16)fabsf(av - bv);
      }
      *(f16x8*)&Arow[q * 16 + c * 8]       = a;    // xs
      *(f16x8*)&Arow[128 + q * 16 + c * 8] = b;    // xt
      *(f16x8*)&Arow[256 + q * 16 + c * 8] = d;    // |xs-xt|
    }
    ds2 += __shfl_xor(ds2, 1); ds2 += __shfl_xor(ds2, 2); ds2 += __shfl_xor(ds2, 4);
    ns2 += __shfl_xor(ns2, 1); ns2 += __shfl_xor(ns2, 2); ns2 += __shfl_xor(ns2, 4);
    nt2 += __shfl_xor(nt2, 1); nt2 += __shfl_xor(nt2, 2); nt2 += __shfl_xor(nt2, 4);
    if (q == 0)
      Arow[529] = (h16)(ds2 / (fmaxf(sqrtf(ns2), EPSC) * fmaxf(sqrtf(nt2), EPSC)));
    for (int j = 530 + q; j < 544; j += 8) Arow[j] = (h16)0.f;   // k-pad
  }
  __syncthreads();

  h16* sHid = sFeat;   // stride 264, overlays features (post-barrier)
  mfma_gemm<32, 256, true>(sFeat, 552, 544, WT + OFF_E1, be1,
      [&](int row, int col, float v) { sHid[row * 264 + col] = (h16)v; });
  mfma_gemm<32, 128, false>(sHid, 264, 256, WT + OFF_E2, be2,
      [&](int row, int col, float v) {
        const h16 vh = (h16)v;
        EB[(size_t)(e0 + row) * 128 + col] = vh;
        sHid[row * 264 + col] = vh;                // e at cols [0,128)
      });
  // park xs (regs) beside e at cols [128,256) of the dead hid overlay
  *(f16x8*)&sFeat[n * 264 + 128 + q * 16]     = xsv0;
  *(f16x8*)&sFeat[n * 264 + 128 + q * 16 + 8] = xsv1;
  __syncthreads();
  mfma_gemm<32, 128, true>(sFeat, 264, 256, WT + OFF_MSG, bmsg,
      [&](int row, int col, float v) {
        atomicAdd(&AGG[(size_t)strg[row] * 128 + col], v);
      });
}

// ---------------------------------------------------------------------------
// K3: xn = relu([x|agg] @ Wnode + b). 64 nodes/block (grid 782, last 16).
// Reads XH fp16 + AGG fp32; writes XNH fp16.
// ---------------------------------------------------------------------------
__global__ __launch_bounds__(256, 4) void k_node_update(
    const h16* __restrict__ XH, const float* __restrict__ AGG,
    const h16* __restrict__ WT, const float* __restrict__ bnode,
    h16* __restrict__ XNH)
{
  __shared__ __align__(16) h16 sA[64 * 264];
  const int tid = threadIdx.x;
  const int n0 = blockIdx.x * 64;
  const int remn = NN - n0;
  const int cnt = remn < 64 ? remn : 64;
  const int n = tid >> 2;
  const int q = tid & 3;

  if (n < cnt) {
    const f16x8* xr = (const f16x8*)&XH[(size_t)(n0 + n) * 128];
    const float4* ar = (const float4*)&AGG[(size_t)(n0 + n) * 128];
    for (int j8 = q; j8 < 16; j8 += 4)
      *(f16x8*)&sA[n * 264 + j8 * 8] = xr[j8];
    for (int j4 = q; j4 < 32; j4 += 4) {
      const float4 b = ar[j4];
      h16* p1 = &sA[n * 264 + 128 + j4 * 4];
      p1[0] = (h16)b.x; p1[1] = (h16)b.y; p1[2] = (h16)b.z; p1[3] = (h16)b.w;
    }
  } else {
    for (int j = q; j < 256; j += 4) sA[n * 264 + j] = (h16)0.f;
  }
  __syncthreads();

  mfma_gemm<64, 128, true>(sA, 264, 256, WT + OFF_NODE, bnode,
      [&](int row, int col, float v) {
        if (row < cnt) XNH[(size_t)(n0 + row) * 128 + col] = (h16)v;
      });
}

// ---------------------------------------------------------------------------
// K4: e_mp = MLP([xn_s|xn_t|e], 384->256->128); pred = MLP(e_mp, 128->64->1).
// 64 edges/block (grid 7813, last 32). All gathers fp16 f16x8 copies.
// sF [64][392] 49KB; overlays: H2 stride 264 @0; e_mp stride 136 @0;
// HC fp32 @byte 17408.
// ---------------------------------------------------------------------------
__global__ __launch_bounds__(256, 3) void k_empl(
    const int* __restrict__ ei, const h16* __restrict__ XNH,
    const h16* __restrict__ EB, const h16* __restrict__ WT,
    const float* __restrict__ bmp1, const float* __restrict__ bmp2,
    const float* __restrict__ bc1,
    const float* __restrict__ Wc2, const float* __restrict__ bc2,
    float* __restrict__ out)
{
  __shared__ __align__(16) h16 sF[64 * 392];
  const int tid = threadIdx.x;
  const long e0 = (long)blockIdx.x * 64;
  const long rem = (long)EE - e0;
  const int cnt = rem < 64 ? (int)rem : 64;
  const int n = tid >> 2;
  const int q = tid & 3;

  if (n < cnt) {
    const int s = ei[e0 + n];
    const int t = ei[(long)EE + e0 + n];
    const f16x8* xsr = (const f16x8*)&XNH[(size_t)s * 128];
    const f16x8* xtr = (const f16x8*)&XNH[(size_t)t * 128];
    const f16x8* ebr = (const f16x8*)&EB[(size_t)(e0 + n) * 128];
    for (int j8 = q; j8 < 16; j8 += 4) {
      *(f16x8*)&sF[n * 392 + j8 * 8]       = xsr[j8];
      *(f16x8*)&sF[n * 392 + 128 + j8 * 8] = xtr[j8];
      *(f16x8*)&sF[n * 392 + 256 + j8 * 8] = ebr[j8];
    }
  } else {
    for (int j = q; j < 384; j += 4) sF[n * 392 + j] = (h16)0.f;
  }
  __syncthreads();

  h16*  sH2 = sF;                              // stride 264
  h16*  sE  = sF;                              // stride 136 (over dead H2)
  float* sHC = (float*)((char*)sF + 17408);    // stride 65 fp32, disjoint
  mfma_gemm<64, 256, true>(sF, 392, 384, WT + OFF_MP1, bmp1,
      [&](int row, int col, float v) { sH2[row * 264 + col] = (h16)v; });
  mfma_gemm<64, 128, false>(sH2, 264, 256, WT + OFF_MP2, bmp2,
      [&](int row, int col, float v) { sE[row * 136 + col] = (h16)v; });
  mfma_gemm<64, 64, true>(sE, 136, 128, WT + OFF_C1, bc1,
      [&](int row, int col, float v) { sHC[row * 65 + col] = v; });
  if (tid < cnt) {
    float acc = bc2[0];
    for (int k = 0; k < 64; ++k) acc += sHC[tid * 65 + k] * Wc2[k];
    out[e0 + tid] = acc;
  }
}

// ---------------------------------------------------------------------------
extern "C" void kernel_launch(void* const* d_in, const int* in_sizes, int n_in,
                              void* d_out, int out_size, void* d_ws, size_t ws_size,
                              hipStream_t stream)
{
  const float* x1  = (const float*)d_in[0];
  const float* x2  = (const float*)d_in[1];
  const int*   ei  = (const int*)d_in[2];
  const float* Wh1 = (const float*)d_in[3],  *bh1 = (const float*)d_in[4];
  const float* Wh2 = (const float*)d_in[5],  *bh2 = (const float*)d_in[6];
  const float* Wl1 = (const float*)d_in[7],  *bl1 = (const float*)d_in[8];
  const float* Wl2 = (const float*)d_in[9],  *bl2 = (const float*)d_in[10];
  const float* We1 = (const float*)d_in[11], *be1 = (const float*)d_in[12];
  const float* We2 = (const float*)d_in[13], *be2 = (const float*)d_in[14];
  const float* Wmsg = (const float*)d_in[15], *bmsg = (const float*)d_in[16];
  const float* Wnode = (const float*)d_in[17], *bnode = (const float*)d_in[18];
  const float* Wmp1 = (const float*)d_in[19], *bmp1 = (const float*)d_in[20];
  const float* Wmp2 = (const float*)d_in[21], *bmp2 = (const float*)d_in[22];
  const float* Wc1 = (const float*)d_in[23], *bc1 = (const float*)d_in[24];
  const float* Wc2 = (const float*)d_in[25], *bc2 = (const float*)d_in[26];
  float* out = (float*)d_out;

  // ws: AGG fp32 | EB fp16 | WT | XH | XNH | X1P | X2H  (~194MB, < 204.8)
  float* AGG = (float*)d_ws;
  h16*   EB  = (h16*)(AGG + (size_t)NN * 128);
  h16*   WT  = EB + (size_t)EE * 128;
  h16*   XH  = WT + WT_TOTAL;
  h16*   XNH = XH + (size_t)NN * 128;
  h16*   X1P = XNH + (size_t)NN * 128;
  h16*   X2H = X1P + (size_t)NN * 16;

  k_prep<<<(WT_TOTAL + 255) / 256, 256, 0, stream>>>(
      We1, We2, Wmsg, Wnode, Wmp1, Wmp2, Wc1, WT);
  k_cvt<<<(NN * 16 + NN * 128 + 255) / 256, 256, 0, stream>>>(x1, x2, X1P, X2H);
  hipMemsetAsync(AGG, 0, (size_t)NN * 128 * sizeof(float), stream);
  k_node_enc<<<12500, 256, 0, stream>>>(x1, x2, Wh1, bh1, Wh2, bh2,
                                        Wl1, bl1, Wl2, bl2, XH);
  k_edge_mlp<<<15625, 256, 0, stream>>>(X1P, X2H, ei, XH, WT,
                                        be1, be2, bmsg, EB, AGG);
  k_node_update<<<782, 256, 0, stream>>>(XH, AGG, WT, bnode, XNH);
  k_empl<<<7813, 256, 0, stream>>>(ei, XNH, EB, WT, bmp1, bmp2, bc1,
                                   Wc2, bc2, out);
}

// Round 2
// 1099.838 us; speedup vs baseline: 1.2216x; 1.1025x over previous
//
#include <hip/hip_runtime.h>
#include <hip/hip_bf16.h>
#include <hip/hip_fp16.h>

// CellTrack GNN, MI355X — R15: templated-K full unroll + 64-edge/512-thr K2.
// R14: 1.213ms; k_edge_mlp 628us, MfmaUtil 13.9%, VALU 15.6%, HBM 13% ->
// ~80% idle, latency-bound. kP was runtime -> no unroll, B loads (L2) not
// prefetched; B traffic 278KB/block x 15625.
// R15: (a) KP/LDA/WAVES compile-time -> full k-loop unroll, deep B prefetch
// (VGPR 52 -> budget 128); (b) k_edge_mlp 64 edges/block, 8 waves: B traffic
// per edge halved, RT=4 doubles MFMA per B load; LDS 73KB, 2 blk/CU = 16
// waves; (c) no trailing barrier after final atomic GEMMs.
// ws: AGG fp32 | EB fp16 | WT fp16 | XH | XNH | X1P | X2H  = ~194MB.

using fp16 = __half;
typedef _Float16 h16;
typedef _Float16 f16x8 __attribute__((ext_vector_type(8)));
typedef float f32x4 __attribute__((ext_vector_type(4)));

#define NN 50000
#define EE 500000
#define EPSC 1e-8f

__device__ __forceinline__ float reluf(float v){ return v > 0.f ? v : 0.f; }

// WT sub-buffer offsets (halves)
#define OFF_E1   0         // [256][544]  (527 real, permuted col order)
#define OFF_E2   139264    // [128][256]
#define OFF_MSG  172032    // [128][256]  ([e|xs] order)
#define OFF_NODE 204800    // [128][256]
#define OFF_MP1  237568    // [256][384]
#define OFF_MP2  335872    // [128][256]
#define OFF_C1   368640    // [64][128]
#define WT_TOTAL 376832

// ---------------------------------------------------------------------------
// k_prep: fp32 weights -> fp16 transposed [n][kP] (zero-pad k >= kreal).
// E1 feature column order (k -> orig We1 row):
//   [0,128) xs -> 142+k | [128,256) xt -> 270+ | [256,384) |xs-xt| -> 398+ |
//   [384,512) |x2s-x2t| -> 13+ | [512,525) |x1s-x1t| -> k-512 |
//   528 sim1 -> 141 | 529 sim2 -> 526 | rest zero.
// MSG order [e|xs]: k<128 -> Wmsg row 128+k ; k>=128 -> Wmsg row k-128.
// ---------------------------------------------------------------------------
__global__ __launch_bounds__(256) void k_prep(
    const float* __restrict__ We1, const float* __restrict__ We2,
    const float* __restrict__ Wmsg, const float* __restrict__ Wnode,
    const float* __restrict__ Wmp1, const float* __restrict__ Wmp2,
    const float* __restrict__ Wc1, h16* __restrict__ WT)
{
  int idx = blockIdx.x * 256 + threadIdx.x;
  if (idx >= WT_TOTAL) return;
  h16 v;
  if (idx < OFF_E2) {
    const int L = idx, n = L / 544, k = L % 544;
    int r;
    if      (k < 128) r = 142 + k;
    else if (k < 256) r = 270 + (k - 128);
    else if (k < 384) r = 398 + (k - 256);
    else if (k < 512) r = 13 + (k - 384);
    else if (k < 525) r = k - 512;
    else if (k == 528) r = 141;
    else if (k == 529) r = 526;
    else r = -1;
    v = (h16)((r >= 0) ? We1[r * 256 + n] : 0.f);
  } else if (idx < OFF_MSG) {
    const int L = idx - OFF_E2, n = L >> 8, k = L & 255;
    v = (h16)We2[k * 128 + n];
  } else if (idx < OFF_NODE) {
    const int L = idx - OFF_MSG, n = L >> 8, k = L & 255;
    const int ko = (k < 128) ? (128 + k) : (k - 128);   // [e|xs] order
    v = (h16)Wmsg[ko * 128 + n];
  } else if (idx < OFF_MP1) {
    const int L = idx - OFF_NODE, n = L >> 8, k = L & 255;
    v = (h16)Wnode[k * 128 + n];
  } else if (idx < OFF_MP2) {
    const int L = idx - OFF_MP1, n = L / 384, k = L % 384;
    v = (h16)Wmp1[k * 256 + n];
  } else if (idx < OFF_C1) {
    const int L = idx - OFF_MP2, n = L >> 8, k = L & 255;
    v = (h16)Wmp2[k * 128 + n];
  } else {
    const int L = idx - OFF_C1, n = L >> 7, k = L & 127;
    v = (h16)Wc1[k * 64 + n];
  }
  WT[idx] = v;
}

// k_cvt: x1 -> fp16 mirror padded to 16/row (vector-gatherable), x2 -> fp16.
__global__ __launch_bounds__(256) void k_cvt(
    const float* __restrict__ x1, const float* __restrict__ x2,
    h16* __restrict__ X1P, h16* __restrict__ X2H)
{
  const int idx = blockIdx.x * 256 + threadIdx.x;
  if (idx < NN * 16) {
    const int nn = idx >> 4, j = idx & 15;
    X1P[idx] = (h16)((j < 13) ? x1[nn * 13 + j] : 0.f);
  }
  const int i2 = idx - NN * 16;
  if (i2 >= 0 && i2 < NN * 128) X2H[i2] = (h16)x2[i2];
}

// ---------------------------------------------------------------------------
// MFMA GEMM: C[ROWS][UDIM] = act(A[ROWS][KP] @ WT^T + b). WAVES waves.
// Wave w: all ROWS x cols [w*UDIM/WAVES..). A fp16 LDS compile-time LDA.
// WT fp16 global [UDIM][KP] (L2-resident). KP compile-time -> full unroll,
// deep B-load prefetch. Barrier before emits (A reads done -> overlays safe);
// trailing barrier optional (skip when kernel ends after emits).
// ---------------------------------------------------------------------------
template<int ROWS, int UDIM, int KP, int LDA, int WAVES, bool RELU,
         bool ENDSYNC, typename F>
__device__ __forceinline__ void mfma_gemm(const h16* sA,
    const h16* __restrict__ WT, const float* __restrict__ bias, F emit)
{
  constexpr int RT = ROWS / 16;
  constexpr int NPW = UDIM / WAVES;
  constexpr int NT = NPW / 16;
  const int tid = threadIdx.x;
  const int wave = tid >> 6;
  const int lane = tid & 63;
  const int m = lane & 15;
  const int quad = lane >> 4;
  const int n0 = wave * NPW;
  f32x4 acc[RT][NT];
#pragma unroll
  for (int r = 0; r < RT; ++r)
#pragma unroll
    for (int j = 0; j < NT; ++j) acc[r][j] = (f32x4){0.f, 0.f, 0.f, 0.f};

#pragma unroll
  for (int k0 = 0; k0 < KP; k0 += 32) {
    f16x8 bf[NT];
#pragma unroll
    for (int j = 0; j < NT; ++j)
      bf[j] = *reinterpret_cast<const f16x8*>(
          &WT[(size_t)(n0 + j * 16 + m) * KP + k0 + quad * 8]);
#pragma unroll
    for (int r = 0; r < RT; ++r) {
      const f16x8 af = *reinterpret_cast<const f16x8*>(
          &sA[(r * 16 + m) * LDA + k0 + quad * 8]);
#pragma unroll
      for (int j = 0; j < NT; ++j)
        acc[r][j] = __builtin_amdgcn_mfma_f32_16x16x32_f16(af, bf[j], acc[r][j], 0, 0, 0);
    }
  }
  __syncthreads();
#pragma unroll
  for (int r = 0; r < RT; ++r)
#pragma unroll
    for (int j = 0; j < NT; ++j) {
      const int col = n0 + j * 16 + m;
      const float bb = bias[col];
#pragma unroll
      for (int g = 0; g < 4; ++g) {
        const int row = r * 16 + quad * 4 + g;
        float v = acc[r][j][g] + bb;
        if (RELU) v = reluf(v);
        emit(row, col, v);
      }
    }
  if (ENDSYNC) __syncthreads();
}

// ---------------------------------------------------------------------------
// K0: node encoder (fp32 VALU). 4 nodes/block. Output: XH fp16.
// ---------------------------------------------------------------------------
__global__ __launch_bounds__(256) void k_node_enc(
    const float* __restrict__ x1, const float* __restrict__ x2,
    const float* __restrict__ Wh1, const float* __restrict__ bh1,
    const float* __restrict__ Wh2, const float* __restrict__ bh2,
    const float* __restrict__ Wl1, const float* __restrict__ bl1,
    const float* __restrict__ Wl2, const float* __restrict__ bl2,
    h16* __restrict__ XH)
{
  __shared__ float sx1[4][13];
  __shared__ float sx2[4][128];
  __shared__ float sh1[4][257];
  __shared__ float sh2[4][257];
  const int tid = threadIdx.x;
  const int node0 = blockIdx.x * 4;

  if (tid < 52) {
    const int n = tid / 13, k = tid % 13;
    sx1[n][k] = x1[(node0 + n) * 13 + k];
  }
  for (int L = tid; L < 512; L += 256) {
    const int n = L >> 7, k = L & 127;
    sx2[n][k] = x2[(size_t)(node0 + n) * 128 + k];
  }
  __syncthreads();

  {
    const int u = tid;
    float a0 = 0.f, a1 = 0.f, a2 = 0.f, a3 = 0.f;
    for (int k = 0; k < 13; ++k) {
      const float w = Wh1[k * 256 + u];
      a0 += sx1[0][k] * w; a1 += sx1[1][k] * w;
      a2 += sx1[2][k] * w; a3 += sx1[3][k] * w;
    }
    const float b = bh1[u];
    sh1[0][u] = reluf(a0 + b); sh1[1][u] = reluf(a1 + b);
    sh1[2][u] = reluf(a2 + b); sh1[3][u] = reluf(a3 + b);

    float c0 = 0.f, c1 = 0.f, c2 = 0.f, c3 = 0.f;
    for (int k = 0; k < 128; ++k) {
      const float w = Wl1[k * 256 + u];
      c0 += sx2[0][k] * w; c1 += sx2[1][k] * w;
      c2 += sx2[2][k] * w; c3 += sx2[3][k] * w;
    }
    const float b2 = bl1[u];
    sh2[0][u] = reluf(c0 + b2); sh2[1][u] = reluf(c1 + b2);
    sh2[2][u] = reluf(c2 + b2); sh2[3][u] = reluf(c3 + b2);
  }
  __syncthreads();

  {
    const int c = tid & 127;
    const int half = tid >> 7;
    float a0 = 0.f, a1 = 0.f;
    if (c < 32) {
      for (int k = 0; k < 256; ++k) {
        const float w = Wh2[k * 32 + c];
        a0 += sh1[half][k] * w; a1 += sh1[half + 2][k] * w;
      }
      const float b = bh2[c];
      XH[(size_t)(node0 + half) * 128 + c]     = (h16)(a0 + b);
      XH[(size_t)(node0 + half + 2) * 128 + c] = (h16)(a1 + b);
    } else {
      const int cc = c - 32;
      for (int k = 0; k < 256; ++k) {
        const float w = Wl2[k * 96 + cc];
        a0 += sh2[half][k] * w; a1 += sh2[half + 2][k] * w;
      }
      const float b = bl2[cc];
      XH[(size_t)(node0 + half) * 128 + c]     = (h16)(a0 + b);
      XH[(size_t)(node0 + half + 2) * 128 + c] = (h16)(a1 + b);
    }
  }
}

// ---------------------------------------------------------------------------
// K2: FUSED edge features + e-MLP (544p->256->128) + msg GEMM + atomic segsum.
// 64 edges/block, 512 thr (8 waves), 8 thr/edge gather, all f16x8.
// sFeat [64][568] 71KB (16B rows); hid/e/xs overlays stride 264. 2 blk/CU.
// Grid 7813 (last block 32 edges -> cnt guards).
// ---------------------------------------------------------------------------
__global__ __launch_bounds__(512, 4) void k_edge_mlp(
    const h16* __restrict__ X1P, const h16* __restrict__ X2H,
    const int* __restrict__ ei, const h16* __restrict__ XH,
    const h16* __restrict__ WT,
    const float* __restrict__ be1, const float* __restrict__ be2,
    const float* __restrict__ bmsg,
    h16* __restrict__ EB, float* __restrict__ AGG)
{
  __shared__ __align__(16) h16 sFeat[64 * 568];
  __shared__ int strg[64];
  const int tid = threadIdx.x;
  const long e0 = (long)blockIdx.x * 64;
  const long rem = (long)EE - e0;
  const int cnt = rem < 64 ? (int)rem : 64;
  const int n = tid >> 3;
  const int q = tid & 7;
  h16* Arow = &sFeat[n * 568];
  f16x8 xsv0 = {}, xsv1 = {};   // xs chunk lives in regs until the msg GEMM

  if (n < cnt) {
    const int s = ei[e0 + n];
    const int t = ei[(long)EE + e0 + n];
    if (q == 0) strg[n] = t;
    float ds = 0.f, ns = 0.f, nt = 0.f;
    if (q < 2) {                                   // handcrafted 13 (pad 16)
      const f16x8 a = *(const f16x8*)&X1P[s * 16 + q * 8];
      const f16x8 b = *(const f16x8*)&X1P[t * 16 + q * 8];
      f16x8 d;
#pragma unroll
      for (int i = 0; i < 8; ++i) {
        const float av = (float)a[i], bv = (float)b[i];
        ds += av * bv; ns += av * av; nt += bv * bv;
        d[i] = (h16)fabsf(av - bv);
      }
      *(f16x8*)&Arow[512 + q * 8] = d;
    }
#pragma unroll
    for (int c = 0; c < 2; ++c) {                  // learned 128
      const f16x8 a = *(const f16x8*)&X2H[(size_t)s * 128 + q * 16 + c * 8];
      const f16x8 b = *(const f16x8*)&X2H[(size_t)t * 128 + q * 16 + c * 8];
      f16x8 d;
#pragma unroll
      for (int i = 0; i < 8; ++i) {
        const float av = (float)a[i], bv = (float)b[i];
        ds += av * bv; ns += av * av; nt += bv * bv;
        d[i] = (h16)fabsf(av - bv);
      }
      *(f16x8*)&Arow[384 + q * 16 + c * 8] = d;
    }
    ds += __shfl_xor(ds, 1); ds += __shfl_xor(ds, 2); ds += __shfl_xor(ds, 4);
    ns += __shfl_xor(ns, 1); ns += __shfl_xor(ns, 2); ns += __shfl_xor(ns, 4);
    nt += __shfl_xor(nt, 1); nt += __shfl_xor(nt, 2); nt += __shfl_xor(nt, 4);
    if (q == 0)
      Arow[528] = (h16)(ds / (fmaxf(sqrtf(ns), EPSC) * fmaxf(sqrtf(nt), EPSC)));

    float ds2 = 0.f, ns2 = 0.f, nt2 = 0.f;
#pragma unroll
    for (int c = 0; c < 2; ++c) {                  // encoded nodes
      const f16x8 a = *(const f16x8*)&XH[(size_t)s * 128 + q * 16 + c * 8];
      const f16x8 b = *(const f16x8*)&XH[(size_t)t * 128 + q * 16 + c * 8];
      if (c == 0) xsv0 = a; else xsv1 = a;
      f16x8 d;
#pragma unroll
      for (int i = 0; i < 8; ++i) {
        const float av = (float)a[i], bv = (float)b[i];
        ds2 += av * bv; ns2 += av * av; nt2 += bv * bv;
        d[i] = (h16)fabsf(av - bv);
      }
      *(f16x8*)&Arow[q * 16 + c * 8]       = a;    // xs
      *(f16x8*)&Arow[128 + q * 16 + c * 8] = b;    // xt
      *(f16x8*)&Arow[256 + q * 16 + c * 8] = d;    // |xs-xt|
    }
    ds2 += __shfl_xor(ds2, 1); ds2 += __shfl_xor(ds2, 2); ds2 += __shfl_xor(ds2, 4);
    ns2 += __shfl_xor(ns2, 1); ns2 += __shfl_xor(ns2, 2); ns2 += __shfl_xor(ns2, 4);
    nt2 += __shfl_xor(nt2, 1); nt2 += __shfl_xor(nt2, 2); nt2 += __shfl_xor(nt2, 4);
    if (q == 0)
      Arow[529] = (h16)(ds2 / (fmaxf(sqrtf(ns2), EPSC) * fmaxf(sqrtf(nt2), EPSC)));
    for (int j = 530 + q; j < 544; j += 8) Arow[j] = (h16)0.f;   // k-pad
  } else {
    if (q == 0) strg[n] = 0;
    for (int j8 = q; j8 < 71; j8 += 8) *(f16x8*)&Arow[j8 * 8] = (f16x8){};
  }
  __syncthreads();

  h16* sHid = sFeat;   // stride 264, overlays features (post-barrier)
  mfma_gemm<64, 256, 544, 568, 8, true, true>(sFeat, WT + OFF_E1, be1,
      [&](int row, int col, float v) { sHid[row * 264 + col] = (h16)v; });
  mfma_gemm<64, 128, 256, 264, 8, false, true>(sHid, WT + OFF_E2, be2,
      [&](int row, int col, float v) {
        const h16 vh = (h16)v;
        if (row < cnt) EB[(size_t)(e0 + row) * 128 + col] = vh;
        sHid[row * 264 + col] = vh;                // e at cols [0,128)
      });
  // park xs (regs) beside e at cols [128,256) of the dead hid overlay
  *(f16x8*)&sFeat[n * 264 + 128 + q * 16]     = xsv0;
  *(f16x8*)&sFeat[n * 264 + 128 + q * 16 + 8] = xsv1;
  __syncthreads();
  mfma_gemm<64, 128, 256, 264, 8, true, false>(sFeat, WT + OFF_MSG, bmsg,
      [&](int row, int col, float v) {
        if (row < cnt) atomicAdd(&AGG[(size_t)strg[row] * 128 + col], v);
      });
}

// ---------------------------------------------------------------------------
// K3: xn = relu([x|agg] @ Wnode + b). 64 nodes/block (grid 782, last 16).
// Reads XH fp16 + AGG fp32; writes XNH fp16.
// ---------------------------------------------------------------------------
__global__ __launch_bounds__(256, 4) void k_node_update(
    const h16* __restrict__ XH, const float* __restrict__ AGG,
    const h16* __restrict__ WT, const float* __restrict__ bnode,
    h16* __restrict__ XNH)
{
  __shared__ __align__(16) h16 sA[64 * 264];
  const int tid = threadIdx.x;
  const int n0 = blockIdx.x * 64;
  const int remn = NN - n0;
  const int cnt = remn < 64 ? remn : 64;
  const int n = tid >> 2;
  const int q = tid & 3;

  if (n < cnt) {
    const f16x8* xr = (const f16x8*)&XH[(size_t)(n0 + n) * 128];
    const float4* ar = (const float4*)&AGG[(size_t)(n0 + n) * 128];
    for (int j8 = q; j8 < 16; j8 += 4)
      *(f16x8*)&sA[n * 264 + j8 * 8] = xr[j8];
    for (int j4 = q; j4 < 32; j4 += 4) {
      const float4 b = ar[j4];
      h16* p1 = &sA[n * 264 + 128 + j4 * 4];
      p1[0] = (h16)b.x; p1[1] = (h16)b.y; p1[2] = (h16)b.z; p1[3] = (h16)b.w;
    }
  } else {
    for (int j = q; j < 256; j += 4) sA[n * 264 + j] = (h16)0.f;
  }
  __syncthreads();

  mfma_gemm<64, 128, 256, 264, 4, true, false>(sA, WT + OFF_NODE, bnode,
      [&](int row, int col, float v) {
        if (row < cnt) XNH[(size_t)(n0 + row) * 128 + col] = (h16)v;
      });
}

// ---------------------------------------------------------------------------
// K4: e_mp = MLP([xn_s|xn_t|e], 384->256->128); pred = MLP(e_mp, 128->64->1).
// 64 edges/block (grid 7813, last 32). All gathers fp16 f16x8 copies.
// sF [64][392] 49KB; overlays: H2 stride 264 @0; e_mp stride 136 @0;
// HC fp32 @byte 17408.
// ---------------------------------------------------------------------------
__global__ __launch_bounds__(256, 3) void k_empl(
    const int* __restrict__ ei, const h16* __restrict__ XNH,
    const h16* __restrict__ EB, const h16* __restrict__ WT,
    const float* __restrict__ bmp1, const float* __restrict__ bmp2,
    const float* __restrict__ bc1,
    const float* __restrict__ Wc2, const float* __restrict__ bc2,
    float* __restrict__ out)
{
  __shared__ __align__(16) h16 sF[64 * 392];
  const int tid = threadIdx.x;
  const long e0 = (long)blockIdx.x * 64;
  const long rem = (long)EE - e0;
  const int cnt = rem < 64 ? (int)rem : 64;
  const int n = tid >> 2;
  const int q = tid & 3;

  if (n < cnt) {
    const int s = ei[e0 + n];
    const int t = ei[(long)EE + e0 + n];
    const f16x8* xsr = (const f16x8*)&XNH[(size_t)s * 128];
    const f16x8* xtr = (const f16x8*)&XNH[(size_t)t * 128];
    const f16x8* ebr = (const f16x8*)&EB[(size_t)(e0 + n) * 128];
    for (int j8 = q; j8 < 16; j8 += 4) {
      *(f16x8*)&sF[n * 392 + j8 * 8]       = xsr[j8];
      *(f16x8*)&sF[n * 392 + 128 + j8 * 8] = xtr[j8];
      *(f16x8*)&sF[n * 392 + 256 + j8 * 8] = ebr[j8];
    }
  } else {
    for (int j = q; j < 384; j += 4) sF[n * 392 + j] = (h16)0.f;
  }
  __syncthreads();

  h16*  sH2 = sF;                              // stride 264
  h16*  sE  = sF;                              // stride 136 (over dead H2)
  float* sHC = (float*)((char*)sF + 17408);    // stride 65 fp32, disjoint
  mfma_gemm<64, 256, 384, 392, 4, true, true>(sF, WT + OFF_MP1, bmp1,
      [&](int row, int col, float v) { sH2[row * 264 + col] = (h16)v; });
  mfma_gemm<64, 128, 256, 264, 4, false, true>(sH2, WT + OFF_MP2, bmp2,
      [&](int row, int col, float v) { sE[row * 136 + col] = (h16)v; });
  mfma_gemm<64, 64, 128, 136, 4, true, true>(sE, WT + OFF_C1, bc1,
      [&](int row, int col, float v) { sHC[row * 65 + col] = v; });
  if (tid < cnt) {
    float acc = bc2[0];
    for (int k = 0; k < 64; ++k) acc += sHC[tid * 65 + k] * Wc2[k];
    out[e0 + tid] = acc;
  }
}

// ---------------------------------------------------------------------------
extern "C" void kernel_launch(void* const* d_in, const int* in_sizes, int n_in,
                              void* d_out, int out_size, void* d_ws, size_t ws_size,
                              hipStream_t stream)
{
  const float* x1  = (const float*)d_in[0];
  const float* x2  = (const float*)d_in[1];
  const int*   ei  = (const int*)d_in[2];
  const float* Wh1 = (const float*)d_in[3],  *bh1 = (const float*)d_in[4];
  const float* Wh2 = (const float*)d_in[5],  *bh2 = (const float*)d_in[6];
  const float* Wl1 = (const float*)d_in[7],  *bl1 = (const float*)d_in[8];
  const float* Wl2 = (const float*)d_in[9],  *bl2 = (const float*)d_in[10];
  const float* We1 = (const float*)d_in[11], *be1 = (const float*)d_in[12];
  const float* We2 = (const float*)d_in[13], *be2 = (const float*)d_in[14];
  const float* Wmsg = (const float*)d_in[15], *bmsg = (const float*)d_in[16];
  const float* Wnode = (const float*)d_in[17], *bnode = (const float*)d_in[18];
  const float* Wmp1 = (const float*)d_in[19], *bmp1 = (const float*)d_in[20];
  const float* Wmp2 = (const float*)d_in[21], *bmp2 = (const float*)d_in[22];
  const float* Wc1 = (const float*)d_in[23], *bc1 = (const float*)d_in[24];
  const float* Wc2 = (const float*)d_in[25], *bc2 = (const float*)d_in[26];
  float* out = (float*)d_out;

  // ws: AGG fp32 | EB fp16 | WT | XH | XNH | X1P | X2H  (~194MB, < 204.8)
  float* AGG = (float*)d_ws;
  h16*   EB  = (h16*)(AGG + (size_t)NN * 128);
  h16*   WT  = EB + (size_t)EE * 128;
  h16*   XH  = WT + WT_TOTAL;
  h16*   XNH = XH + (size_t)NN * 128;
  h16*   X1P = XNH + (size_t)NN * 128;
  h16*   X2H = X1P + (size_t)NN * 16;

  k_prep<<<(WT_TOTAL + 255) / 256, 256, 0, stream>>>(
      We1, We2, Wmsg, Wnode, Wmp1, Wmp2, Wc1, WT);
  k_cvt<<<(NN * 16 + NN * 128 + 255) / 256, 256, 0, stream>>>(x1, x2, X1P, X2H);
  hipMemsetAsync(AGG, 0, (size_t)NN * 128 * sizeof(float), stream);
  k_node_enc<<<12500, 256, 0, stream>>>(x1, x2, Wh1, bh1, Wh2, bh2,
                                        Wl1, bl1, Wl2, bl2, XH);
  k_edge_mlp<<<7813, 512, 0, stream>>>(X1P, X2H, ei, XH, WT,
                                       be1, be2, bmsg, EB, AGG);
  k_node_update<<<782, 256, 0, stream>>>(XH, AGG, WT, bnode, XNH);
  k_empl<<<7813, 256, 0, stream>>>(ei, XNH, EB, WT, bmp1, bmp2, bc1,
                                   Wc2, bc2, out);
}

// Round 3
// 1044.401 us; speedup vs baseline: 1.2864x; 1.0531x over previous
//
#include <hip/hip_runtime.h>
#include <hip/hip_bf16.h>
#include <hip/hip_fp16.h>

// CellTrack GNN, MI355X — R16: explicit B register double-buffer + 8-wave k_empl.
// R15: 1.100ms; k_edge_mlp 486us, VGPR 52 -> compiler issued B loads at use
// (no prefetch), k-steps serialized on ~200cyc L2 latency. k_empl ~300us at
// 37.5% occ with same issue.
// R16: (a) mfma_gemm: named bcur/bnxt f16x8 double-buffer, loads forced ~2
// k-steps ahead; bias preloaded; active-wave guard for UDIM<16*WAVES;
// (b) k_empl 512 thr / 8 waves (2 blk/CU, 50% occ); (c) k_edge_mlp barrier
// merged (xs park inside GEMM2 post-emit window).
// ws: AGG fp32 | EB fp16 | WT fp16 | XH | XNH | X1P | X2H  = ~194MB.

using fp16 = __half;
typedef _Float16 h16;
typedef _Float16 f16x8 __attribute__((ext_vector_type(8)));
typedef float f32x4 __attribute__((ext_vector_type(4)));

#define NN 50000
#define EE 500000
#define EPSC 1e-8f

__device__ __forceinline__ float reluf(float v){ return v > 0.f ? v : 0.f; }

// WT sub-buffer offsets (halves)
#define OFF_E1   0         // [256][544]  (527 real, permuted col order)
#define OFF_E2   139264    // [128][256]
#define OFF_MSG  172032    // [128][256]  ([e|xs] order)
#define OFF_NODE 204800    // [128][256]
#define OFF_MP1  237568    // [256][384]
#define OFF_MP2  335872    // [128][256]
#define OFF_C1   368640    // [64][128]
#define WT_TOTAL 376832

// ---------------------------------------------------------------------------
// k_prep: fp32 weights -> fp16 transposed [n][kP] (zero-pad k >= kreal).
// E1 feature column order (k -> orig We1 row):
//   [0,128) xs -> 142+k | [128,256) xt -> 270+ | [256,384) |xs-xt| -> 398+ |
//   [384,512) |x2s-x2t| -> 13+ | [512,525) |x1s-x1t| -> k-512 |
//   528 sim1 -> 141 | 529 sim2 -> 526 | rest zero.
// MSG order [e|xs]: k<128 -> Wmsg row 128+k ; k>=128 -> Wmsg row k-128.
// ---------------------------------------------------------------------------
__global__ __launch_bounds__(256) void k_prep(
    const float* __restrict__ We1, const float* __restrict__ We2,
    const float* __restrict__ Wmsg, const float* __restrict__ Wnode,
    const float* __restrict__ Wmp1, const float* __restrict__ Wmp2,
    const float* __restrict__ Wc1, h16* __restrict__ WT)
{
  int idx = blockIdx.x * 256 + threadIdx.x;
  if (idx >= WT_TOTAL) return;
  h16 v;
  if (idx < OFF_E2) {
    const int L = idx, n = L / 544, k = L % 544;
    int r;
    if      (k < 128) r = 142 + k;
    else if (k < 256) r = 270 + (k - 128);
    else if (k < 384) r = 398 + (k - 256);
    else if (k < 512) r = 13 + (k - 384);
    else if (k < 525) r = k - 512;
    else if (k == 528) r = 141;
    else if (k == 529) r = 526;
    else r = -1;
    v = (h16)((r >= 0) ? We1[r * 256 + n] : 0.f);
  } else if (idx < OFF_MSG) {
    const int L = idx - OFF_E2, n = L >> 8, k = L & 255;
    v = (h16)We2[k * 128 + n];
  } else if (idx < OFF_NODE) {
    const int L = idx - OFF_MSG, n = L >> 8, k = L & 255;
    const int ko = (k < 128) ? (128 + k) : (k - 128);   // [e|xs] order
    v = (h16)Wmsg[ko * 128 + n];
  } else if (idx < OFF_MP1) {
    const int L = idx - OFF_NODE, n = L >> 8, k = L & 255;
    v = (h16)Wnode[k * 128 + n];
  } else if (idx < OFF_MP2) {
    const int L = idx - OFF_MP1, n = L / 384, k = L % 384;
    v = (h16)Wmp1[k * 256 + n];
  } else if (idx < OFF_C1) {
    const int L = idx - OFF_MP2, n = L >> 8, k = L & 255;
    v = (h16)Wmp2[k * 128 + n];
  } else {
    const int L = idx - OFF_C1, n = L >> 7, k = L & 127;
    v = (h16)Wc1[k * 64 + n];
  }
  WT[idx] = v;
}

// k_cvt: x1 -> fp16 mirror padded to 16/row (vector-gatherable), x2 -> fp16.
__global__ __launch_bounds__(256) void k_cvt(
    const float* __restrict__ x1, const float* __restrict__ x2,
    h16* __restrict__ X1P, h16* __restrict__ X2H)
{
  const int idx = blockIdx.x * 256 + threadIdx.x;
  if (idx < NN * 16) {
    const int nn = idx >> 4, j = idx & 15;
    X1P[idx] = (h16)((j < 13) ? x1[nn * 13 + j] : 0.f);
  }
  const int i2 = idx - NN * 16;
  if (i2 >= 0 && i2 < NN * 128) X2H[i2] = (h16)x2[i2];
}

// ---------------------------------------------------------------------------
// MFMA GEMM: C[ROWS][UDIM] = act(A[ROWS][KP] @ WT^T + b). WAVES waves.
// Wave w: all ROWS x cols [w*NPW..). NPW >= 16; waves with n0 >= UDIM idle
// (but hit barriers). B loads double-buffered in registers 2 k-steps deep
// (bcur/bnxt, compile-time indexed) -> L2 latency overlapped with MFMA.
// Barrier before emits (A reads done -> overlays safe); ENDSYNC optional.
// ---------------------------------------------------------------------------
template<int ROWS, int UDIM, int KP, int LDA, int WAVES, bool RELU,
         bool ENDSYNC, typename F>
__device__ __forceinline__ void mfma_gemm(const h16* sA,
    const h16* __restrict__ WT, const float* __restrict__ bias, F emit)
{
  constexpr int RT = ROWS / 16;
  constexpr int NPW0 = UDIM / WAVES;
  constexpr int NPW = (NPW0 < 16) ? 16 : NPW0;
  constexpr int NT = NPW / 16;
  constexpr int NSTEPS = KP / 32;
  const int tid = threadIdx.x;
  const int wave = tid >> 6;
  const int lane = tid & 63;
  const int m = lane & 15;
  const int quad = lane >> 4;
  const int n0 = wave * NPW;
  const bool active = (n0 < UDIM);

  f32x4 acc[RT][NT];
#pragma unroll
  for (int r = 0; r < RT; ++r)
#pragma unroll
    for (int j = 0; j < NT; ++j) acc[r][j] = (f32x4){0.f, 0.f, 0.f, 0.f};
  float bb[NT];

  if (active) {
    const h16* wbase = &WT[(size_t)(n0 + m) * KP + quad * 8];
#pragma unroll
    for (int j = 0; j < NT; ++j) bb[j] = bias[n0 + j * 16 + m];

    f16x8 bcur[2][NT], bnxt[2][NT];
#pragma unroll
    for (int s = 0; s < 2; ++s)
      if (s < NSTEPS)
#pragma unroll
        for (int j = 0; j < NT; ++j)
          bcur[s][j] = *(const f16x8*)&wbase[(size_t)j * 16 * KP + s * 32];

#pragma unroll
    for (int ss = 0; ss < NSTEPS; ss += 2) {
      // prefetch steps ss+2, ss+3
#pragma unroll
      for (int s = 0; s < 2; ++s)
        if (ss + 2 + s < NSTEPS)
#pragma unroll
          for (int j = 0; j < NT; ++j)
            bnxt[s][j] = *(const f16x8*)&wbase[(size_t)j * 16 * KP + (ss + 2 + s) * 32];
      // compute steps ss, ss+1
#pragma unroll
      for (int s = 0; s < 2; ++s)
        if (ss + s < NSTEPS) {
          const int k0 = (ss + s) * 32;
#pragma unroll
          for (int r = 0; r < RT; ++r) {
            const f16x8 af = *(const f16x8*)&sA[(r * 16 + m) * LDA + k0 + quad * 8];
#pragma unroll
            for (int j = 0; j < NT; ++j)
              acc[r][j] = __builtin_amdgcn_mfma_f32_16x16x32_f16(af, bcur[s][j], acc[r][j], 0, 0, 0);
          }
        }
      // rotate
#pragma unroll
      for (int s = 0; s < 2; ++s)
        if (ss + 2 + s < NSTEPS)
#pragma unroll
          for (int j = 0; j < NT; ++j) bcur[s][j] = bnxt[s][j];
    }
  }
  __syncthreads();
  if (active) {
#pragma unroll
    for (int j = 0; j < NT; ++j) {
      const int col = n0 + j * 16 + m;
#pragma unroll
      for (int r = 0; r < RT; ++r)
#pragma unroll
        for (int g = 0; g < 4; ++g) {
          const int row = r * 16 + quad * 4 + g;
          float v = acc[r][j][g] + bb[j];
          if (RELU) v = reluf(v);
          emit(row, col, v);
        }
    }
  }
  if (ENDSYNC) __syncthreads();
}

// ---------------------------------------------------------------------------
// K0: node encoder (fp32 VALU). 4 nodes/block. Output: XH fp16.
// ---------------------------------------------------------------------------
__global__ __launch_bounds__(256) void k_node_enc(
    const float* __restrict__ x1, const float* __restrict__ x2,
    const float* __restrict__ Wh1, const float* __restrict__ bh1,
    const float* __restrict__ Wh2, const float* __restrict__ bh2,
    const float* __restrict__ Wl1, const float* __restrict__ bl1,
    const float* __restrict__ Wl2, const float* __restrict__ bl2,
    h16* __restrict__ XH)
{
  __shared__ float sx1[4][13];
  __shared__ float sx2[4][128];
  __shared__ float sh1[4][257];
  __shared__ float sh2[4][257];
  const int tid = threadIdx.x;
  const int node0 = blockIdx.x * 4;

  if (tid < 52) {
    const int n = tid / 13, k = tid % 13;
    sx1[n][k] = x1[(node0 + n) * 13 + k];
  }
  for (int L = tid; L < 512; L += 256) {
    const int n = L >> 7, k = L & 127;
    sx2[n][k] = x2[(size_t)(node0 + n) * 128 + k];
  }
  __syncthreads();

  {
    const int u = tid;
    float a0 = 0.f, a1 = 0.f, a2 = 0.f, a3 = 0.f;
    for (int k = 0; k < 13; ++k) {
      const float w = Wh1[k * 256 + u];
      a0 += sx1[0][k] * w; a1 += sx1[1][k] * w;
      a2 += sx1[2][k] * w; a3 += sx1[3][k] * w;
    }
    const float b = bh1[u];
    sh1[0][u] = reluf(a0 + b); sh1[1][u] = reluf(a1 + b);
    sh1[2][u] = reluf(a2 + b); sh1[3][u] = reluf(a3 + b);

    float c0 = 0.f, c1 = 0.f, c2 = 0.f, c3 = 0.f;
    for (int k = 0; k < 128; ++k) {
      const float w = Wl1[k * 256 + u];
      c0 += sx2[0][k] * w; c1 += sx2[1][k] * w;
      c2 += sx2[2][k] * w; c3 += sx2[3][k] * w;
    }
    const float b2 = bl1[u];
    sh2[0][u] = reluf(c0 + b2); sh2[1][u] = reluf(c1 + b2);
    sh2[2][u] = reluf(c2 + b2); sh2[3][u] = reluf(c3 + b2);
  }
  __syncthreads();

  {
    const int c = tid & 127;
    const int half = tid >> 7;
    float a0 = 0.f, a1 = 0.f;
    if (c < 32) {
      for (int k = 0; k < 256; ++k) {
        const float w = Wh2[k * 32 + c];
        a0 += sh1[half][k] * w; a1 += sh1[half + 2][k] * w;
      }
      const float b = bh2[c];
      XH[(size_t)(node0 + half) * 128 + c]     = (h16)(a0 + b);
      XH[(size_t)(node0 + half + 2) * 128 + c] = (h16)(a1 + b);
    } else {
      const int cc = c - 32;
      for (int k = 0; k < 256; ++k) {
        const float w = Wl2[k * 96 + cc];
        a0 += sh2[half][k] * w; a1 += sh2[half + 2][k] * w;
      }
      const float b = bl2[cc];
      XH[(size_t)(node0 + half) * 128 + c]     = (h16)(a0 + b);
      XH[(size_t)(node0 + half + 2) * 128 + c] = (h16)(a1 + b);
    }
  }
}

// ---------------------------------------------------------------------------
// K2: FUSED edge features + e-MLP (544p->256->128) + msg GEMM + atomic segsum.
// 64 edges/block, 512 thr (8 waves), 8 thr/edge gather, all f16x8.
// sFeat [64][568] 71KB (16B rows); hid/e/xs overlays stride 264. 2 blk/CU.
// Grid 7813 (last block 32 edges -> cnt guards).
// ---------------------------------------------------------------------------
__global__ __launch_bounds__(512, 4) void k_edge_mlp(
    const h16* __restrict__ X1P, const h16* __restrict__ X2H,
    const int* __restrict__ ei, const h16* __restrict__ XH,
    const h16* __restrict__ WT,
    const float* __restrict__ be1, const float* __restrict__ be2,
    const float* __restrict__ bmsg,
    h16* __restrict__ EB, float* __restrict__ AGG)
{
  __shared__ __align__(16) h16 sFeat[64 * 568];
  __shared__ int strg[64];
  const int tid = threadIdx.x;
  const long e0 = (long)blockIdx.x * 64;
  const long rem = (long)EE - e0;
  const int cnt = rem < 64 ? (int)rem : 64;
  const int n = tid >> 3;
  const int q = tid & 7;
  h16* Arow = &sFeat[n * 568];
  f16x8 xsv0 = {}, xsv1 = {};   // xs chunk lives in regs until the msg GEMM

  if (n < cnt) {
    const int s = ei[e0 + n];
    const int t = ei[(long)EE + e0 + n];
    if (q == 0) strg[n] = t;
    float ds = 0.f, ns = 0.f, nt = 0.f;
    if (q < 2) {                                   // handcrafted 13 (pad 16)
      const f16x8 a = *(const f16x8*)&X1P[s * 16 + q * 8];
      const f16x8 b = *(const f16x8*)&X1P[t * 16 + q * 8];
      f16x8 d;
#pragma unroll
      for (int i = 0; i < 8; ++i) {
        const float av = (float)a[i], bv = (float)b[i];
        ds += av * bv; ns += av * av; nt += bv * bv;
        d[i] = (h16)fabsf(av - bv);
      }
      *(f16x8*)&Arow[512 + q * 8] = d;
    }
#pragma unroll
    for (int c = 0; c < 2; ++c) {                  // learned 128
      const f16x8 a = *(const f16x8*)&X2H[(size_t)s * 128 + q * 16 + c * 8];
      const f16x8 b = *(const f16x8*)&X2H[(size_t)t * 128 + q * 16 + c * 8];
      f16x8 d;
#pragma unroll
      for (int i = 0; i < 8; ++i) {
        const float av = (float)a[i], bv = (float)b[i];
        ds += av * bv; ns += av * av; nt += bv * bv;
        d[i] = (h16)fabsf(av - bv);
      }
      *(f16x8*)&Arow[384 + q * 16 + c * 8] = d;
    }
    ds += __shfl_xor(ds, 1); ds += __shfl_xor(ds, 2); ds += __shfl_xor(ds, 4);
    ns += __shfl_xor(ns, 1); ns += __shfl_xor(ns, 2); ns += __shfl_xor(ns, 4);
    nt += __shfl_xor(nt, 1); nt += __shfl_xor(nt, 2); nt += __shfl_xor(nt, 4);
    if (q == 0)
      Arow[528] = (h16)(ds / (fmaxf(sqrtf(ns), EPSC) * fmaxf(sqrtf(nt), EPSC)));

    float ds2 = 0.f, ns2 = 0.f, nt2 = 0.f;
#pragma unroll
    for (int c = 0; c < 2; ++c) {                  // encoded nodes
      const f16x8 a = *(const f16x8*)&XH[(size_t)s * 128 + q * 16 + c * 8];
      const f16x8 b = *(const f16x8*)&XH[(size_t)t * 128 + q * 16 + c * 8];
      if (c == 0) xsv0 = a; else xsv1 = a;
      f16x8 d;
#pragma unroll
      for (int i = 0; i < 8; ++i) {
        const float av = (float)a[i], bv = (float)b[i];
        ds2 += av * bv; ns2 += av * av; nt2 += bv * bv;
        d[i] = (h16)fabsf(av - bv);
      }
      *(f16x8*)&Arow[q * 16 + c * 8]       = a;    // xs
      *(f16x8*)&Arow[128 + q * 16 + c * 8] = b;    // xt
      *(f16x8*)&Arow[256 + q * 16 + c * 8] = d;    // |xs-xt|
    }
    ds2 += __shfl_xor(ds2, 1); ds2 += __shfl_xor(ds2, 2); ds2 += __shfl_xor(ds2, 4);
    ns2 += __shfl_xor(ns2, 1); ns2 += __shfl_xor(ns2, 2); ns2 += __shfl_xor(ns2, 4);
    nt2 += __shfl_xor(nt2, 1); nt2 += __shfl_xor(nt2, 2); nt2 += __shfl_xor(nt2, 4);
    if (q == 0)
      Arow[529] = (h16)(ds2 / (fmaxf(sqrtf(ns2), EPSC) * fmaxf(sqrtf(nt2), EPSC)));
    for (int j = 530 + q; j < 544; j += 8) Arow[j] = (h16)0.f;   // k-pad
  } else {
    if (q == 0) strg[n] = 0;
    for (int j8 = q; j8 < 71; j8 += 8) *(f16x8*)&Arow[j8 * 8] = (f16x8){};
  }
  __syncthreads();

  h16* sHid = sFeat;   // stride 264, overlays features (post-barrier)
  mfma_gemm<64, 256, 544, 568, 8, true, true>(sFeat, WT + OFF_E1, be1,
      [&](int row, int col, float v) { sHid[row * 264 + col] = (h16)v; });
  mfma_gemm<64, 128, 256, 264, 8, false, false>(sHid, WT + OFF_E2, be2,
      [&](int row, int col, float v) {
        const h16 vh = (h16)v;
        if (row < cnt) EB[(size_t)(e0 + row) * 128 + col] = vh;
        sHid[row * 264 + col] = vh;                // e at cols [0,128)
      });
  // park xs (regs) beside e at cols [128,256): same post-A-read window as
  // GEMM2's emit (disjoint cols) -> single barrier covers both.
  *(f16x8*)&sFeat[n * 264 + 128 + q * 16]     = xsv0;
  *(f16x8*)&sFeat[n * 264 + 128 + q * 16 + 8] = xsv1;
  __syncthreads();
  mfma_gemm<64, 128, 256, 264, 8, true, false>(sFeat, WT + OFF_MSG, bmsg,
      [&](int row, int col, float v) {
        if (row < cnt) atomicAdd(&AGG[(size_t)strg[row] * 128 + col], v);
      });
}

// ---------------------------------------------------------------------------
// K3: xn = relu([x|agg] @ Wnode + b). 64 nodes/block (grid 782, last 16).
// Reads XH fp16 + AGG fp32; writes XNH fp16.
// ---------------------------------------------------------------------------
__global__ __launch_bounds__(256, 4) void k_node_update(
    const h16* __restrict__ XH, const float* __restrict__ AGG,
    const h16* __restrict__ WT, const float* __restrict__ bnode,
    h16* __restrict__ XNH)
{
  __shared__ __align__(16) h16 sA[64 * 264];
  const int tid = threadIdx.x;
  const int n0 = blockIdx.x * 64;
  const int remn = NN - n0;
  const int cnt = remn < 64 ? remn : 64;
  const int n = tid >> 2;
  const int q = tid & 3;

  if (n < cnt) {
    const f16x8* xr = (const f16x8*)&XH[(size_t)(n0 + n) * 128];
    const float4* ar = (const float4*)&AGG[(size_t)(n0 + n) * 128];
    for (int j8 = q; j8 < 16; j8 += 4)
      *(f16x8*)&sA[n * 264 + j8 * 8] = xr[j8];
    for (int j4 = q; j4 < 32; j4 += 4) {
      const float4 b = ar[j4];
      h16* p1 = &sA[n * 264 + 128 + j4 * 4];
      p1[0] = (h16)b.x; p1[1] = (h16)b.y; p1[2] = (h16)b.z; p1[3] = (h16)b.w;
    }
  } else {
    for (int j = q; j < 256; j += 4) sA[n * 264 + j] = (h16)0.f;
  }
  __syncthreads();

  mfma_gemm<64, 128, 256, 264, 4, true, false>(sA, WT + OFF_NODE, bnode,
      [&](int row, int col, float v) {
        if (row < cnt) XNH[(size_t)(n0 + row) * 128 + col] = (h16)v;
      });
}

// ---------------------------------------------------------------------------
// K4: e_mp = MLP([xn_s|xn_t|e], 384->256->128); pred = MLP(e_mp, 128->64->1).
// 64 edges/block, 512 thr (8 waves), grid 7813 (last 32). Gathers f16x8.
// sF [64][392] 49KB; overlays: H2 stride 264 @0; e_mp stride 136 @0;
// HC fp32 @byte 17408. 2 blk/CU, 16 waves.
// ---------------------------------------------------------------------------
__global__ __launch_bounds__(512, 4) void k_empl(
    const int* __restrict__ ei, const h16* __restrict__ XNH,
    const h16* __restrict__ EB, const h16* __restrict__ WT,
    const float* __restrict__ bmp1, const float* __restrict__ bmp2,
    const float* __restrict__ bc1,
    const float* __restrict__ Wc2, const float* __restrict__ bc2,
    float* __restrict__ out)
{
  __shared__ __align__(16) h16 sF[64 * 392];
  const int tid = threadIdx.x;
  const long e0 = (long)blockIdx.x * 64;
  const long rem = (long)EE - e0;
  const int cnt = rem < 64 ? (int)rem : 64;
  const int n = tid >> 3;
  const int q = tid & 7;

  if (n < cnt) {
    const int s = ei[e0 + n];
    const int t = ei[(long)EE + e0 + n];
    const f16x8* xsr = (const f16x8*)&XNH[(size_t)s * 128];
    const f16x8* xtr = (const f16x8*)&XNH[(size_t)t * 128];
    const f16x8* ebr = (const f16x8*)&EB[(size_t)(e0 + n) * 128];
#pragma unroll
    for (int j8 = q; j8 < 16; j8 += 8) {
      *(f16x8*)&sF[n * 392 + j8 * 8]       = xsr[j8];
      *(f16x8*)&sF[n * 392 + 128 + j8 * 8] = xtr[j8];
      *(f16x8*)&sF[n * 392 + 256 + j8 * 8] = ebr[j8];
    }
  } else {
    for (int j8 = q; j8 < 49; j8 += 8) *(f16x8*)&sF[n * 392 + j8 * 8] = (f16x8){};
  }
  __syncthreads();

  h16*  sH2 = sF;                              // stride 264
  h16*  sE  = sF;                              // stride 136 (over dead H2)
  float* sHC = (float*)((char*)sF + 17408);    // stride 65 fp32, disjoint
  mfma_gemm<64, 256, 384, 392, 8, true, true>(sF, WT + OFF_MP1, bmp1,
      [&](int row, int col, float v) { sH2[row * 264 + col] = (h16)v; });
  mfma_gemm<64, 128, 256, 264, 8, false, true>(sH2, WT + OFF_MP2, bmp2,
      [&](int row, int col, float v) { sE[row * 136 + col] = (h16)v; });
  mfma_gemm<64, 64, 128, 136, 8, true, true>(sE, WT + OFF_C1, bc1,
      [&](int row, int col, float v) { sHC[row * 65 + col] = v; });
  if (tid < cnt) {
    float acc = bc2[0];
    for (int k = 0; k < 64; ++k) acc += sHC[tid * 65 + k] * Wc2[k];
    out[e0 + tid] = acc;
  }
}

// ---------------------------------------------------------------------------
extern "C" void kernel_launch(void* const* d_in, const int* in_sizes, int n_in,
                              void* d_out, int out_size, void* d_ws, size_t ws_size,
                              hipStream_t stream)
{
  const float* x1  = (const float*)d_in[0];
  const float* x2  = (const float*)d_in[1];
  const int*   ei  = (const int*)d_in[2];
  const float* Wh1 = (const float*)d_in[3],  *bh1 = (const float*)d_in[4];
  const float* Wh2 = (const float*)d_in[5],  *bh2 = (const float*)d_in[6];
  const float* Wl1 = (const float*)d_in[7],  *bl1 = (const float*)d_in[8];
  const float* Wl2 = (const float*)d_in[9],  *bl2 = (const float*)d_in[10];
  const float* We1 = (const float*)d_in[11], *be1 = (const float*)d_in[12];
  const float* We2 = (const float*)d_in[13], *be2 = (const float*)d_in[14];
  const float* Wmsg = (const float*)d_in[15], *bmsg = (const float*)d_in[16];
  const float* Wnode = (const float*)d_in[17], *bnode = (const float*)d_in[18];
  const float* Wmp1 = (const float*)d_in[19], *bmp1 = (const float*)d_in[20];
  const float* Wmp2 = (const float*)d_in[21], *bmp2 = (const float*)d_in[22];
  const float* Wc1 = (const float*)d_in[23], *bc1 = (const float*)d_in[24];
  const float* Wc2 = (const float*)d_in[25], *bc2 = (const float*)d_in[26];
  float* out = (float*)d_out;

  // ws: AGG fp32 | EB fp16 | WT | XH | XNH | X1P | X2H  (~194MB, < 204.8)
  float* AGG = (float*)d_ws;
  h16*   EB  = (h16*)(AGG + (size_t)NN * 128);
  h16*   WT  = EB + (size_t)EE * 128;
  h16*   XH  = WT + WT_TOTAL;
  h16*   XNH = XH + (size_t)NN * 128;
  h16*   X1P = XNH + (size_t)NN * 128;
  h16*   X2H = X1P + (size_t)NN * 16;

  k_prep<<<(WT_TOTAL + 255) / 256, 256, 0, stream>>>(
      We1, We2, Wmsg, Wnode, Wmp1, Wmp2, Wc1, WT);
  k_cvt<<<(NN * 16 + NN * 128 + 255) / 256, 256, 0, stream>>>(x1, x2, X1P, X2H);
  hipMemsetAsync(AGG, 0, (size_t)NN * 128 * sizeof(float), stream);
  k_node_enc<<<12500, 256, 0, stream>>>(x1, x2, Wh1, bh1, Wh2, bh2,
                                        Wl1, bl1, Wl2, bl2, XH);
  k_edge_mlp<<<7813, 512, 0, stream>>>(X1P, X2H, ei, XH, WT,
                                       be1, be2, bmsg, EB, AGG);
  k_node_update<<<782, 256, 0, stream>>>(XH, AGG, WT, bnode, XNH);
  k_empl<<<7813, 512, 0, stream>>>(ei, XNH, EB, WT, bmp1, bmp2, bc1,
                                   Wc2, bc2, out);
}

// Round 4
// 858.381 us; speedup vs baseline: 1.5652x; 1.2167x over previous
//
#include <hip/hip_runtime.h>
#include <hip/hip_bf16.h>
#include <hip/hip_fp16.h>

// CellTrack GNN, MI355X — R17: fence-pinned B-prefetch pipeline + MFMA node enc.
// R16: 1.044ms; k_edge_mlp 452us, VGPR stuck at 52 -> compiler folded the
// bcur/bnxt rotation and re-sank B loads to uses; still L2-latency bound
// (Mfma 19.7 / VALU 28.6 / HBM 18).
// R17: (a) mfma_gemm: copy-free ping-pong breg[2][CHUNK][NT] with
// asm volatile("":::"memory") fences -> loads of chunk c+1 legally CANNOT
// sink below fence c+1, so they overlap chunk c's MFMAs (true SW pipeline);
// (b) k_node_enc -> k_nenc: 32 nodes/block fp16 MFMA ([x1|x2] 160 -> 512
// hidden (block-diag W1) -> 128 out), weights+fused biases prepped by k_prep.
// ws: AGG fp32 | EB fp16 | WT fp16 | XH | XNH | X1P | X2H | BF fp32.

using fp16 = __half;
typedef _Float16 h16;
typedef _Float16 f16x8 __attribute__((ext_vector_type(8)));
typedef float f32x4 __attribute__((ext_vector_type(4)));

#define NN 50000
#define EE 500000
#define EPSC 1e-8f

__device__ __forceinline__ float reluf(float v){ return v > 0.f ? v : 0.f; }

// WT sub-buffer offsets (halves)
#define OFF_E1   0         // [256][544]  (527 real, permuted col order)
#define OFF_E2   139264    // [128][256]
#define OFF_MSG  172032    // [128][256]  ([e|xs] order)
#define OFF_NODE 204800    // [128][256]
#define OFF_MP1  237568    // [256][384]
#define OFF_MP2  335872    // [128][256]
#define OFF_C1   368640    // [64][128]
#define OFF_N1   376832    // [512][160]  block-diag [Wh1 | Wl1]
#define OFF_N2   458752    // [128][512]  block-diag [Wh2 ; Wl2]
#define WT_TOTAL 524288
// fused biases (fp32, after WT): BF[0..511]=[bh1|bl1], BF[512..639]=[bh2|bl2]
#define BF_TOTAL 640

// ---------------------------------------------------------------------------
// k_prep: fp32 weights -> fp16 transposed [n][kP] (zero-pad k >= kreal).
// E1 feature column order (k -> orig We1 row):
//   [0,128) xs -> 142+k | [128,256) xt -> 270+ | [256,384) |xs-xt| -> 398+ |
//   [384,512) |x2s-x2t| -> 13+ | [512,525) |x1s-x1t| -> k-512 |
//   528 sim1 -> 141 | 529 sim2 -> 526 | rest zero.
// MSG order [e|xs]: k<128 -> Wmsg row 128+k ; k>=128 -> Wmsg row k-128.
// N1: n<256: hid1, k<13 -> Wh1[k][n]; n>=256: hid2, 16<=k<144 -> Wl1[k-16][n-256].
// N2: n<32: k<256 -> Wh2[k][n]; n>=32: k>=256 -> Wl2[k-256][n-32].
// ---------------------------------------------------------------------------
__global__ __launch_bounds__(256) void k_prep(
    const float* __restrict__ We1, const float* __restrict__ We2,
    const float* __restrict__ Wmsg, const float* __restrict__ Wnode,
    const float* __restrict__ Wmp1, const float* __restrict__ Wmp2,
    const float* __restrict__ Wc1,
    const float* __restrict__ Wh1, const float* __restrict__ Wl1,
    const float* __restrict__ Wh2, const float* __restrict__ Wl2,
    const float* __restrict__ bh1, const float* __restrict__ bl1,
    const float* __restrict__ bh2, const float* __restrict__ bl2,
    h16* __restrict__ WT, float* __restrict__ BF)
{
  int idx = blockIdx.x * 256 + threadIdx.x;
  if (idx >= WT_TOTAL) {
    const int b = idx - WT_TOTAL;
    if (b < 512) BF[b] = (b < 256) ? bh1[b] : bl1[b - 256];
    else if (b < BF_TOTAL) {
      const int c = b - 512;
      BF[b] = (c < 32) ? bh2[c] : bl2[c - 32];
    }
    return;
  }
  h16 v;
  if (idx < OFF_E2) {
    const int L = idx, n = L / 544, k = L % 544;
    int r;
    if      (k < 128) r = 142 + k;
    else if (k < 256) r = 270 + (k - 128);
    else if (k < 384) r = 398 + (k - 256);
    else if (k < 512) r = 13 + (k - 384);
    else if (k < 525) r = k - 512;
    else if (k == 528) r = 141;
    else if (k == 529) r = 526;
    else r = -1;
    v = (h16)((r >= 0) ? We1[r * 256 + n] : 0.f);
  } else if (idx < OFF_MSG) {
    const int L = idx - OFF_E2, n = L >> 8, k = L & 255;
    v = (h16)We2[k * 128 + n];
  } else if (idx < OFF_NODE) {
    const int L = idx - OFF_MSG, n = L >> 8, k = L & 255;
    const int ko = (k < 128) ? (128 + k) : (k - 128);   // [e|xs] order
    v = (h16)Wmsg[ko * 128 + n];
  } else if (idx < OFF_MP1) {
    const int L = idx - OFF_NODE, n = L >> 8, k = L & 255;
    v = (h16)Wnode[k * 128 + n];
  } else if (idx < OFF_MP2) {
    const int L = idx - OFF_MP1, n = L / 384, k = L % 384;
    v = (h16)Wmp1[k * 256 + n];
  } else if (idx < OFF_C1) {
    const int L = idx - OFF_MP2, n = L >> 8, k = L & 255;
    v = (h16)Wmp2[k * 128 + n];
  } else if (idx < OFF_N1) {
    const int L = idx - OFF_C1, n = L >> 7, k = L & 127;
    v = (h16)Wc1[k * 64 + n];
  } else if (idx < OFF_N2) {
    const int L = idx - OFF_N1, n = L / 160, k = L % 160;
    float f = 0.f;
    if (n < 256) { if (k < 13) f = Wh1[k * 256 + n]; }
    else { if (k >= 16 && k < 144) f = Wl1[(k - 16) * 256 + (n - 256)]; }
    v = (h16)f;
  } else {
    const int L = idx - OFF_N2, n = L >> 9, k = L & 511;
    float f = 0.f;
    if (n < 32) { if (k < 256) f = Wh2[k * 32 + n]; }
    else { if (k >= 256) f = Wl2[(k - 256) * 96 + (n - 32)]; }
    v = (h16)f;
  }
  WT[idx] = v;
}

// k_cvt: x1 -> fp16 mirror padded to 16/row (vector-gatherable), x2 -> fp16.
__global__ __launch_bounds__(256) void k_cvt(
    const float* __restrict__ x1, const float* __restrict__ x2,
    h16* __restrict__ X1P, h16* __restrict__ X2H)
{
  const int idx = blockIdx.x * 256 + threadIdx.x;
  if (idx < NN * 16) {
    const int nn = idx >> 4, j = idx & 15;
    X1P[idx] = (h16)((j < 13) ? x1[nn * 13 + j] : 0.f);
  }
  const int i2 = idx - NN * 16;
  if (i2 >= 0 && i2 < NN * 128) X2H[i2] = (h16)x2[i2];
}

// ---------------------------------------------------------------------------
// MFMA GEMM: C[ROWS][UDIM] = act(A[ROWS][KP] @ WT^T + b). WAVES waves.
// B loads pipelined in CHUNK-step ping-pong registers; asm memory fences pin
// each chunk's loads before the fence -> they overlap the previous chunk's
// MFMAs and cannot be re-sunk by the scheduler (the R16 failure mode).
// Barrier before emits (A reads done -> overlays safe); ENDSYNC optional.
// ---------------------------------------------------------------------------
template<int ROWS, int UDIM, int KP, int LDA, int WAVES, bool RELU,
         bool ENDSYNC, typename F>
__device__ __forceinline__ void mfma_gemm(const h16* sA,
    const h16* __restrict__ WT, const float* __restrict__ bias, F emit)
{
  constexpr int RT = ROWS / 16;
  constexpr int NPW0 = UDIM / WAVES;
  constexpr int NPW = (NPW0 < 16) ? 16 : NPW0;
  constexpr int NT = NPW / 16;
  constexpr int NSTEPS = KP / 32;
  constexpr int CH0 = (NT >= 4) ? 2 : 4;
  constexpr int CHUNK = (NSTEPS < CH0) ? NSTEPS : CH0;
  constexpr int NCH = (NSTEPS + CHUNK - 1) / CHUNK;
  const int tid = threadIdx.x;
  const int wave = tid >> 6;
  const int lane = tid & 63;
  const int m = lane & 15;
  const int quad = lane >> 4;
  const int n0 = wave * NPW;
  const bool active = (n0 < UDIM);

  f32x4 acc[RT][NT];
#pragma unroll
  for (int r = 0; r < RT; ++r)
#pragma unroll
    for (int j = 0; j < NT; ++j) acc[r][j] = (f32x4){0.f, 0.f, 0.f, 0.f};
  float bb[NT];

  if (active) {
    const h16* wbase = &WT[(size_t)(n0 + m) * KP + quad * 8];
#pragma unroll
    for (int j = 0; j < NT; ++j) bb[j] = bias[n0 + j * 16 + m];

    f16x8 breg[2][CHUNK][NT];
    // prologue: chunk 0
#pragma unroll
    for (int s = 0; s < CHUNK; ++s)
      if (s < NSTEPS)
#pragma unroll
        for (int j = 0; j < NT; ++j)
          breg[0][s][j] = *(const f16x8*)&wbase[(size_t)j * 16 * KP + s * 32];
    asm volatile("" ::: "memory");

#pragma unroll
    for (int c = 0; c < NCH; ++c) {
      // issue chunk c+1 loads (must stay above the fence below -> they
      // overlap chunk c's MFMAs; parity index is compile-time under unroll)
      if (c + 1 < NCH) {
#pragma unroll
        for (int s = 0; s < CHUNK; ++s) {
          const int st = (c + 1) * CHUNK + s;
          if (st < NSTEPS)
#pragma unroll
            for (int j = 0; j < NT; ++j)
              breg[(c + 1) & 1][s][j] =
                  *(const f16x8*)&wbase[(size_t)j * 16 * KP + st * 32];
        }
      }
      // compute chunk c
#pragma unroll
      for (int s = 0; s < CHUNK; ++s) {
        const int st = c * CHUNK + s;
        if (st < NSTEPS) {
          const int k0 = st * 32;
#pragma unroll
          for (int r = 0; r < RT; ++r) {
            const f16x8 af = *(const f16x8*)&sA[(r * 16 + m) * LDA + k0 + quad * 8];
#pragma unroll
            for (int j = 0; j < NT; ++j)
              acc[r][j] = __builtin_amdgcn_mfma_f32_16x16x32_f16(af, breg[c & 1][s][j], acc[r][j], 0, 0, 0);
          }
        }
      }
      asm volatile("" ::: "memory");
    }
  }
  __syncthreads();
  if (active) {
#pragma unroll
    for (int j = 0; j < NT; ++j) {
      const int col = n0 + j * 16 + m;
#pragma unroll
      for (int r = 0; r < RT; ++r)
#pragma unroll
        for (int g = 0; g < 4; ++g) {
          const int row = r * 16 + quad * 4 + g;
          float v = acc[r][j][g] + bb[j];
          if (RELU) v = reluf(v);
          emit(row, col, v);
        }
    }
  }
  if (ENDSYNC) __syncthreads();
}

// ---------------------------------------------------------------------------
// K0: node encoder via MFMA. 32 nodes/block, 512 thr (grid 1563, last 16).
// sA [32][168]: [x1P(16) | x2(128) | 0(16)]; L1 -> sH [32][520] (512 hidden,
// block-diag W1) ; L2 -> XH[128]. Biases from fused BF.
// ---------------------------------------------------------------------------
__global__ __launch_bounds__(512, 4) void k_nenc(
    const h16* __restrict__ X1P, const h16* __restrict__ X2H,
    const h16* __restrict__ WT, const float* __restrict__ BF,
    h16* __restrict__ XH)
{
  __shared__ __align__(16) h16 sA[32 * 168];
  __shared__ __align__(16) h16 sH[32 * 520];
  const int tid = threadIdx.x;
  const int n0 = blockIdx.x * 32;
  const int remn = NN - n0;
  const int cnt = remn < 32 ? remn : 32;
  const int n = tid >> 4;
  const int q = tid & 15;

  if (n < cnt) {
    const int node = n0 + n;
    if (q < 2)
      *(f16x8*)&sA[n * 168 + q * 8] = *(const f16x8*)&X1P[node * 16 + q * 8];
    else if (q < 4)
      *(f16x8*)&sA[n * 168 + 144 + (q - 2) * 8] = (f16x8){};
    *(f16x8*)&sA[n * 168 + 16 + q * 8] =
        *(const f16x8*)&X2H[(size_t)node * 128 + q * 8];
  }
  __syncthreads();

  mfma_gemm<32, 512, 160, 168, 8, true, true>(sA, WT + OFF_N1, BF,
      [&](int row, int col, float v) { sH[row * 520 + col] = (h16)v; });
  mfma_gemm<32, 128, 512, 520, 8, false, false>(sH, WT + OFF_N2, BF + 512,
      [&](int row, int col, float v) {
        if (row < cnt) XH[(size_t)(n0 + row) * 128 + col] = (h16)v;
      });
}

// ---------------------------------------------------------------------------
// K2: FUSED edge features + e-MLP (544p->256->128) + msg GEMM + atomic segsum.
// 64 edges/block, 512 thr (8 waves), 8 thr/edge gather, all f16x8.
// sFeat [64][568] 71KB (16B rows); hid/e/xs overlays stride 264. 2 blk/CU.
// Grid 7813 (last block 32 edges -> cnt guards).
// ---------------------------------------------------------------------------
__global__ __launch_bounds__(512, 4) void k_edge_mlp(
    const h16* __restrict__ X1P, const h16* __restrict__ X2H,
    const int* __restrict__ ei, const h16* __restrict__ XH,
    const h16* __restrict__ WT,
    const float* __restrict__ be1, const float* __restrict__ be2,
    const float* __restrict__ bmsg,
    h16* __restrict__ EB, float* __restrict__ AGG)
{
  __shared__ __align__(16) h16 sFeat[64 * 568];
  __shared__ int strg[64];
  const int tid = threadIdx.x;
  const long e0 = (long)blockIdx.x * 64;
  const long rem = (long)EE - e0;
  const int cnt = rem < 64 ? (int)rem : 64;
  const int n = tid >> 3;
  const int q = tid & 7;
  h16* Arow = &sFeat[n * 568];
  f16x8 xsv0 = {}, xsv1 = {};   // xs chunk lives in regs until the msg GEMM

  if (n < cnt) {
    const int s = ei[e0 + n];
    const int t = ei[(long)EE + e0 + n];
    if (q == 0) strg[n] = t;
    float ds = 0.f, ns = 0.f, nt = 0.f;
    if (q < 2) {                                   // handcrafted 13 (pad 16)
      const f16x8 a = *(const f16x8*)&X1P[s * 16 + q * 8];
      const f16x8 b = *(const f16x8*)&X1P[t * 16 + q * 8];
      f16x8 d;
#pragma unroll
      for (int i = 0; i < 8; ++i) {
        const float av = (float)a[i], bv = (float)b[i];
        ds += av * bv; ns += av * av; nt += bv * bv;
        d[i] = (h16)fabsf(av - bv);
      }
      *(f16x8*)&Arow[512 + q * 8] = d;
    }
#pragma unroll
    for (int c = 0; c < 2; ++c) {                  // learned 128
      const f16x8 a = *(const f16x8*)&X2H[(size_t)s * 128 + q * 16 + c * 8];
      const f16x8 b = *(const f16x8*)&X2H[(size_t)t * 128 + q * 16 + c * 8];
      f16x8 d;
#pragma unroll
      for (int i = 0; i < 8; ++i) {
        const float av = (float)a[i], bv = (float)b[i];
        ds += av * bv; ns += av * av; nt += bv * bv;
        d[i] = (h16)fabsf(av - bv);
      }
      *(f16x8*)&Arow[384 + q * 16 + c * 8] = d;
    }
    ds += __shfl_xor(ds, 1); ds += __shfl_xor(ds, 2); ds += __shfl_xor(ds, 4);
    ns += __shfl_xor(ns, 1); ns += __shfl_xor(ns, 2); ns += __shfl_xor(ns, 4);
    nt += __shfl_xor(nt, 1); nt += __shfl_xor(nt, 2); nt += __shfl_xor(nt, 4);
    if (q == 0)
      Arow[528] = (h16)(ds / (fmaxf(sqrtf(ns), EPSC) * fmaxf(sqrtf(nt), EPSC)));

    float ds2 = 0.f, ns2 = 0.f, nt2 = 0.f;
#pragma unroll
    for (int c = 0; c < 2; ++c) {                  // encoded nodes
      const f16x8 a = *(const f16x8*)&XH[(size_t)s * 128 + q * 16 + c * 8];
      const f16x8 b = *(const f16x8*)&XH[(size_t)t * 128 + q * 16 + c * 8];
      if (c == 0) xsv0 = a; else xsv1 = a;
      f16x8 d;
#pragma unroll
      for (int i = 0; i < 8; ++i) {
        const float av = (float)a[i], bv = (float)b[i];
        ds2 += av * bv; ns2 += av * av; nt2 += bv * bv;
        d[i] = (h16)fabsf(av - bv);
      }
      *(f16x8*)&Arow[q * 16 + c * 8]       = a;    // xs
      *(f16x8*)&Arow[128 + q * 16 + c * 8] = b;    // xt
      *(f16x8*)&Arow[256 + q * 16 + c * 8] = d;    // |xs-xt|
    }
    ds2 += __shfl_xor(ds2, 1); ds2 += __shfl_xor(ds2, 2); ds2 += __shfl_xor(ds2, 4);
    ns2 += __shfl_xor(ns2, 1); ns2 += __shfl_xor(ns2, 2); ns2 += __shfl_xor(ns2, 4);
    nt2 += __shfl_xor(nt2, 1); nt2 += __shfl_xor(nt2, 2); nt2 += __shfl_xor(nt2, 4);
    if (q == 0)
      Arow[529] = (h16)(ds2 / (fmaxf(sqrtf(ns2), EPSC) * fmaxf(sqrtf(nt2), EPSC)));
    for (int j = 530 + q; j < 544; j += 8) Arow[j] = (h16)0.f;   // k-pad
  } else {
    if (q == 0) strg[n] = 0;
    for (int j8 = q; j8 < 71; j8 += 8) *(f16x8*)&Arow[j8 * 8] = (f16x8){};
  }
  __syncthreads();

  h16* sHid = sFeat;   // stride 264, overlays features (post-barrier)
  mfma_gemm<64, 256, 544, 568, 8, true, true>(sFeat, WT + OFF_E1, be1,
      [&](int row, int col, float v) { sHid[row * 264 + col] = (h16)v; });
  mfma_gemm<64, 128, 256, 264, 8, false, false>(sHid, WT + OFF_E2, be2,
      [&](int row, int col, float v) {
        const h16 vh = (h16)v;
        if (row < cnt) EB[(size_t)(e0 + row) * 128 + col] = vh;
        sHid[row * 264 + col] = vh;                // e at cols [0,128)
      });
  // park xs (regs) beside e at cols [128,256): same post-A-read window as
  // GEMM2's emit (disjoint cols) -> single barrier covers both.
  *(f16x8*)&sFeat[n * 264 + 128 + q * 16]     = xsv0;
  *(f16x8*)&sFeat[n * 264 + 128 + q * 16 + 8] = xsv1;
  __syncthreads();
  mfma_gemm<64, 128, 256, 264, 8, true, false>(sFeat, WT + OFF_MSG, bmsg,
      [&](int row, int col, float v) {
        if (row < cnt) atomicAdd(&AGG[(size_t)strg[row] * 128 + col], v);
      });
}

// ---------------------------------------------------------------------------
// K3: xn = relu([x|agg] @ Wnode + b). 64 nodes/block (grid 782, last 16).
// Reads XH fp16 + AGG fp32; writes XNH fp16.
// ---------------------------------------------------------------------------
__global__ __launch_bounds__(256, 4) void k_node_update(
    const h16* __restrict__ XH, const float* __restrict__ AGG,
    const h16* __restrict__ WT, const float* __restrict__ bnode,
    h16* __restrict__ XNH)
{
  __shared__ __align__(16) h16 sA[64 * 264];
  const int tid = threadIdx.x;
  const int n0 = blockIdx.x * 64;
  const int remn = NN - n0;
  const int cnt = remn < 64 ? remn : 64;
  const int n = tid >> 2;
  const int q = tid & 3;

  if (n < cnt) {
    const f16x8* xr = (const f16x8*)&XH[(size_t)(n0 + n) * 128];
    const float4* ar = (const float4*)&AGG[(size_t)(n0 + n) * 128];
    for (int j8 = q; j8 < 16; j8 += 4)
      *(f16x8*)&sA[n * 264 + j8 * 8] = xr[j8];
    for (int j4 = q; j4 < 32; j4 += 4) {
      const float4 b = ar[j4];
      h16* p1 = &sA[n * 264 + 128 + j4 * 4];
      p1[0] = (h16)b.x; p1[1] = (h16)b.y; p1[2] = (h16)b.z; p1[3] = (h16)b.w;
    }
  } else {
    for (int j = q; j < 256; j += 4) sA[n * 264 + j] = (h16)0.f;
  }
  __syncthreads();

  mfma_gemm<64, 128, 256, 264, 4, true, false>(sA, WT + OFF_NODE, bnode,
      [&](int row, int col, float v) {
        if (row < cnt) XNH[(size_t)(n0 + row) * 128 + col] = (h16)v;
      });
}

// ---------------------------------------------------------------------------
// K4: e_mp = MLP([xn_s|xn_t|e], 384->256->128); pred = MLP(e_mp, 128->64->1).
// 64 edges/block, 512 thr (8 waves), grid 7813 (last 32). Gathers f16x8.
// sF [64][392] 49KB; overlays: H2 stride 264 @0; e_mp stride 136 @0;
// HC fp32 @byte 17408.
// ---------------------------------------------------------------------------
__global__ __launch_bounds__(512, 4) void k_empl(
    const int* __restrict__ ei, const h16* __restrict__ XNH,
    const h16* __restrict__ EB, const h16* __restrict__ WT,
    const float* __restrict__ bmp1, const float* __restrict__ bmp2,
    const float* __restrict__ bc1,
    const float* __restrict__ Wc2, const float* __restrict__ bc2,
    float* __restrict__ out)
{
  __shared__ __align__(16) h16 sF[64 * 392];
  const int tid = threadIdx.x;
  const long e0 = (long)blockIdx.x * 64;
  const long rem = (long)EE - e0;
  const int cnt = rem < 64 ? (int)rem : 64;
  const int n = tid >> 3;
  const int q = tid & 7;

  if (n < cnt) {
    const int s = ei[e0 + n];
    const int t = ei[(long)EE + e0 + n];
    const f16x8* xsr = (const f16x8*)&XNH[(size_t)s * 128];
    const f16x8* xtr = (const f16x8*)&XNH[(size_t)t * 128];
    const f16x8* ebr = (const f16x8*)&EB[(size_t)(e0 + n) * 128];
#pragma unroll
    for (int j8 = q; j8 < 16; j8 += 8) {
      *(f16x8*)&sF[n * 392 + j8 * 8]       = xsr[j8];
      *(f16x8*)&sF[n * 392 + 128 + j8 * 8] = xtr[j8];
      *(f16x8*)&sF[n * 392 + 256 + j8 * 8] = ebr[j8];
    }
  } else {
    for (int j8 = q; j8 < 49; j8 += 8) *(f16x8*)&sF[n * 392 + j8 * 8] = (f16x8){};
  }
  __syncthreads();

  h16*  sH2 = sF;                              // stride 264
  h16*  sE  = sF;                              // stride 136 (over dead H2)
  float* sHC = (float*)((char*)sF + 17408);    // stride 65 fp32, disjoint
  mfma_gemm<64, 256, 384, 392, 8, true, true>(sF, WT + OFF_MP1, bmp1,
      [&](int row, int col, float v) { sH2[row * 264 + col] = (h16)v; });
  mfma_gemm<64, 128, 256, 264, 8, false, true>(sH2, WT + OFF_MP2, bmp2,
      [&](int row, int col, float v) { sE[row * 136 + col] = (h16)v; });
  mfma_gemm<64, 64, 128, 136, 8, true, true>(sE, WT + OFF_C1, bc1,
      [&](int row, int col, float v) { sHC[row * 65 + col] = v; });
  if (tid < cnt) {
    float acc = bc2[0];
    for (int k = 0; k < 64; ++k) acc += sHC[tid * 65 + k] * Wc2[k];
    out[e0 + tid] = acc;
  }
}

// ---------------------------------------------------------------------------
extern "C" void kernel_launch(void* const* d_in, const int* in_sizes, int n_in,
                              void* d_out, int out_size, void* d_ws, size_t ws_size,
                              hipStream_t stream)
{
  const float* x1  = (const float*)d_in[0];
  const float* x2  = (const float*)d_in[1];
  const int*   ei  = (const int*)d_in[2];
  const float* Wh1 = (const float*)d_in[3],  *bh1 = (const float*)d_in[4];
  const float* Wh2 = (const float*)d_in[5],  *bh2 = (const float*)d_in[6];
  const float* Wl1 = (const float*)d_in[7],  *bl1 = (const float*)d_in[8];
  const float* Wl2 = (const float*)d_in[9],  *bl2 = (const float*)d_in[10];
  const float* We1 = (const float*)d_in[11], *be1 = (const float*)d_in[12];
  const float* We2 = (const float*)d_in[13], *be2 = (const float*)d_in[14];
  const float* Wmsg = (const float*)d_in[15], *bmsg = (const float*)d_in[16];
  const float* Wnode = (const float*)d_in[17], *bnode = (const float*)d_in[18];
  const float* Wmp1 = (const float*)d_in[19], *bmp1 = (const float*)d_in[20];
  const float* Wmp2 = (const float*)d_in[21], *bmp2 = (const float*)d_in[22];
  const float* Wc1 = (const float*)d_in[23], *bc1 = (const float*)d_in[24];
  const float* Wc2 = (const float*)d_in[25], *bc2 = (const float*)d_in[26];
  float* out = (float*)d_out;

  // ws: AGG fp32 | EB fp16 | WT | XH | XNH | X1P | X2H | BF fp32 (~195MB)
  float* AGG = (float*)d_ws;
  h16*   EB  = (h16*)(AGG + (size_t)NN * 128);
  h16*   WT  = EB + (size_t)EE * 128;
  h16*   XH  = WT + WT_TOTAL;
  h16*   XNH = XH + (size_t)NN * 128;
  h16*   X1P = XNH + (size_t)NN * 128;
  h16*   X2H = X1P + (size_t)NN * 16;
  float* BF  = (float*)(X2H + (size_t)NN * 128);

  k_prep<<<(WT_TOTAL + BF_TOTAL + 255) / 256, 256, 0, stream>>>(
      We1, We2, Wmsg, Wnode, Wmp1, Wmp2, Wc1,
      Wh1, Wl1, Wh2, Wl2, bh1, bl1, bh2, bl2, WT, BF);
  k_cvt<<<(NN * 16 + NN * 128 + 255) / 256, 256, 0, stream>>>(x1, x2, X1P, X2H);
  hipMemsetAsync(AGG, 0, (size_t)NN * 128 * sizeof(float), stream);
  k_nenc<<<(NN + 31) / 32, 512, 0, stream>>>(X1P, X2H, WT, BF, XH);
  k_edge_mlp<<<7813, 512, 0, stream>>>(X1P, X2H, ei, XH, WT,
                                       be1, be2, bmsg, EB, AGG);
  k_node_update<<<782, 256, 0, stream>>>(XH, AGG, WT, bnode, XNH);
  k_empl<<<7813, 512, 0, stream>>>(ei, XNH, EB, WT, bmp1, bmp2, bc1,
                                   Wc2, bc2, out);
}